// Round 2
// baseline (1877.636 us; speedup 1.0000x reference)
//
#include <hip/hip_runtime.h>
#include <float.h>

#define BB 8
#define NN 4096
#define DD 64
#define KNBR 10
#define ROWS (BB*NN)   // 32768

// ---------------- K1: BN stats (sum, sumsq per feature) ----------------
__global__ void k_bn_stats(const float* __restrict__ x, float* __restrict__ stats) {
  __shared__ float ls[2][4][64];
  int d = threadIdx.x & 63;
  int g = threadIdx.x >> 6;
  float s = 0.f, s2 = 0.f;
  for (int r = blockIdx.x * 4 + g; r < ROWS; r += gridDim.x * 4) {
    float val = x[r * 64 + d];
    s += val;
    s2 = fmaf(val, val, s2);
  }
  ls[0][g][d] = s;
  ls[1][g][d] = s2;
  __syncthreads();
  if (g == 0) {
    atomicAdd(&stats[d],      ls[0][0][d] + ls[0][1][d] + ls[0][2][d] + ls[0][3][d]);
    atomicAdd(&stats[64 + d], ls[1][0][d] + ls[1][1][d] + ls[1][2][d] + ls[1][3][d]);
  }
}

// ---------------- K2: finalize scale/shift ----------------
__global__ void k_bn_finalize(const float* __restrict__ stats,
                              const float* __restrict__ gamma,
                              const float* __restrict__ beta,
                              float* __restrict__ ss) {
  int d = threadIdx.x;  // 64 threads
  const float inv = 1.f / 32768.f;
  float mu  = stats[d] * inv;
  float var = stats[64 + d] * inv - mu * mu;
  float sc  = gamma[d] / sqrtf(var + 1e-5f);
  ss[d]      = sc;
  ss[64 + d] = beta[d] - mu * sc;
}

// ---------------- K3: normalize + per-row sum of squares ----------------
__global__ void k_normalize(const float* __restrict__ x, const float* __restrict__ ss,
                            float* __restrict__ xn, float* __restrict__ sq) {
  int row = blockIdx.x * 4 + (threadIdx.x >> 6);
  int d = threadIdx.x & 63;
  float val = fmaf(x[row * 64 + d], ss[d], ss[64 + d]);
  xn[row * 64 + d] = val;
  float p = val * val;
  #pragma unroll
  for (int off = 32; off > 0; off >>= 1) p += __shfl_xor(p, off);
  if (d == 0) sq[row] = p;
}

// ---------------- K4: KNN (top-10 smallest dist per row) ----------------
// block = 256 thr = 4 waves; block owns 64 rows (lane = row); wave w owns
// m-range [w*1024,(w+1)*1024) in 16 LDS-staged tiles of 64. dist ordering
// uses sq[m] - 2*dot (sq[row] constant per row -> same order as reference).
// knn[] stores GLOBAL row indices (b*NN + m).
__global__ __launch_bounds__(256, 2) void k_knn(const float* __restrict__ xn,
                                                const float* __restrict__ sq,
                                                int* __restrict__ knn) {
  __shared__ float smem[16384];   // 64 KB: 4 tiles of [64][64]
  __shared__ float sqs[4][64];
  const int tid = threadIdx.x;
  const int w = tid >> 6, lane = tid & 63;
  const int b = blockIdx.x >> 6;
  const int rowbase = (blockIdx.x & 63) << 6;
  const float* xb = xn + b * NN * 64;

  // cache this lane's row in registers
  float4 rr[16];
  {
    const float4* rp = (const float4*)(xb + (rowbase + lane) * 64);
    #pragma unroll
    for (int i = 0; i < 16; ++i) rr[i] = rp[i];
  }

  float bd[10]; int bi[10];
  #pragma unroll
  for (int i = 0; i < 10; ++i) { bd[i] = FLT_MAX; bi[i] = 0; }

  float* tile = smem + w * 4096;
  for (int t = 0; t < 16; ++t) {
    const int mbase = (w * 16 + t) << 6;
    {
      const float4* s4 = (const float4*)(xb + mbase * 64);
      float4* d4 = (float4*)tile;
      #pragma unroll
      for (int i = 0; i < 16; ++i) d4[i * 64 + lane] = s4[i * 64 + lane];
      sqs[w][lane] = sq[b * NN + mbase + lane];
    }
    __syncthreads();
    #pragma unroll 1
    for (int m = 0; m < 64; ++m) {
      const float4* Mr = (const float4*)(tile + m * 64);
      float a0 = 0.f, a1 = 0.f, a2 = 0.f, a3 = 0.f;
      #pragma unroll
      for (int i = 0; i < 16; i += 4) {
        float4 q0 = Mr[i], q1 = Mr[i + 1], q2 = Mr[i + 2], q3 = Mr[i + 3];
        a0 = fmaf(rr[i].x, q0.x, fmaf(rr[i].y, q0.y, fmaf(rr[i].z, q0.z, fmaf(rr[i].w, q0.w, a0))));
        a1 = fmaf(rr[i+1].x, q1.x, fmaf(rr[i+1].y, q1.y, fmaf(rr[i+1].z, q1.z, fmaf(rr[i+1].w, q1.w, a1))));
        a2 = fmaf(rr[i+2].x, q2.x, fmaf(rr[i+2].y, q2.y, fmaf(rr[i+2].z, q2.z, fmaf(rr[i+2].w, q2.w, a2))));
        a3 = fmaf(rr[i+3].x, q3.x, fmaf(rr[i+3].y, q3.y, fmaf(rr[i+3].z, q3.z, fmaf(rr[i+3].w, q3.w, a3))));
      }
      float dist = fmaf(-2.f, (a0 + a1) + (a2 + a3), sqs[w][m]);
      if (dist < bd[9]) {       // rare: sorted-insert ladder, static indices only
        float cd = dist; int ci = mbase + m;
        #pragma unroll
        for (int j = 0; j < 10; ++j) {
          bool sw = cd < bd[j];
          float tf = bd[j]; int ti = bi[j];
          bd[j] = sw ? cd : tf; bi[j] = sw ? ci : ti;
          cd = sw ? tf : cd;    ci = sw ? ti : ci;
        }
      }
    }
    __syncthreads();
  }

  // merge the 4 per-wave top-10 lists per row
  float* md = smem;                   // [4][64][10] dists (reuses tile space)
  int*   mi = (int*)(smem + 2560);    // [4][64][10] indices
  #pragma unroll
  for (int i = 0; i < 10; ++i) {
    md[(w * 64 + lane) * 10 + i] = bd[i];
    mi[(w * 64 + lane) * 10 + i] = bi[i];
  }
  __syncthreads();
  if (tid < 64) {
    float fd[10]; int fi[10];
    #pragma unroll
    for (int i = 0; i < 10; ++i) { fd[i] = FLT_MAX; fi[i] = 0; }
    for (int w2 = 0; w2 < 4; ++w2) {
      for (int kk = 0; kk < 10; ++kk) {
        float dd = md[(w2 * 64 + tid) * 10 + kk];
        int   ii = mi[(w2 * 64 + tid) * 10 + kk];
        if (dd < fd[9]) {
          float cd = dd; int ci = ii;
          #pragma unroll
          for (int j = 0; j < 10; ++j) {
            bool sw = cd < fd[j];
            float tf = fd[j]; int ti = fi[j];
            fd[j] = sw ? cd : tf; fi[j] = sw ? ci : ti;
            cd = sw ? tf : cd;    ci = sw ? ti : ci;
          }
        }
      }
    }
    #pragma unroll
    for (int kk = 0; kk < 10; ++kk)
      knn[(b * NN + rowbase + tid) * KNBR + kk] = b * NN + fi[kk];  // GLOBAL index
  }
}

// ---------------- K5: U/V precompute (layer-1 folded per point) ----------------
// U[n][o] = sum_d xn[n][d]*(W1[d][o]+W1[64+d][o]) + b1[o]
// V[n][o] = sum_d xn[n][d]*W1[64+d][o]      -> h1(edge n,m) = relu(U[n]-V[m])
__global__ void k_uv(const float* __restrict__ xn, const float* __restrict__ W1,
                     const float* __restrict__ b1, float* __restrict__ u,
                     float* __restrict__ v) {
  __shared__ float wa[64 * 128];
  __shared__ float wb[64 * 128];
  int tid = threadIdx.x;
  for (int i = tid; i < 8192; i += 256) {
    int d = i >> 7, o = i & 127;
    float bw = W1[(64 + d) * 128 + o];
    wb[i] = bw;
    wa[i] = W1[d * 128 + o] + bw;
  }
  __syncthreads();
  int o = tid & 127, half = tid >> 7;
  float bb = b1[o];
  for (int j = 0; j < 64; ++j) {
    int n = blockIdx.x * 128 + half + 2 * j;
    float au0 = bb, au1 = 0.f, av0 = 0.f, av1 = 0.f;
    #pragma unroll
    for (int d = 0; d < 64; d += 2) {
      float x0 = xn[n * 64 + d], x1 = xn[n * 64 + d + 1];
      au0 = fmaf(x0, wa[d * 128 + o], au0);
      av0 = fmaf(x0, wb[d * 128 + o], av0);
      au1 = fmaf(x1, wa[(d + 1) * 128 + o], au1);
      av1 = fmaf(x1, wb[(d + 1) * 128 + o], av1);
    }
    u[n * 128 + o] = au0 + au1;
    v[n * 128 + o] = av0 + av1;
  }
}

// ---------------- K6: edge MLP (h1->h2->h3) + max over K ----------------
__global__ __launch_bounds__(256, 3) void k_edge(const float* __restrict__ u,
                                                 const float* __restrict__ v,
                                                 const int* __restrict__ knn,
                                                 const float* __restrict__ W2,
                                                 const float* __restrict__ b2,
                                                 const float* __restrict__ W3,
                                                 const float* __restrict__ b3,
                                                 float* __restrict__ vert) {
  __shared__ float W2s[128 * 64];
  __shared__ float W3s[64 * 64];
  __shared__ float h1s[4][128];
  __shared__ float h2s[4][64];
  int tid = threadIdx.x, w = tid >> 6, lane = tid & 63;
  for (int i = tid; i < 128 * 64; i += 256) W2s[i] = W2[i];
  for (int i = tid; i < 64 * 64; i += 256)  W3s[i] = W3[i];
  __syncthreads();
  float bias2 = b2[lane], bias3 = b3[lane];
  int gw = blockIdx.x * 4 + w;
  for (int j = 0; j < 4; ++j) {
    int n = gw + 8192 * j;
    float u0 = u[n * 128 + lane], u1 = u[n * 128 + 64 + lane];
    float vmax = 0.f;
    for (int k = 0; k < KNBR; ++k) {
      int m = knn[n * KNBR + k];
      h1s[w][lane]      = fmaxf(u0 - v[m * 128 + lane], 0.f);
      h1s[w][lane + 64] = fmaxf(u1 - v[m * 128 + 64 + lane], 0.f);
      __syncthreads();
      float ac0 = bias2, ac1 = 0.f, ac2 = 0.f, ac3 = 0.f;
      #pragma unroll
      for (int i = 0; i < 128; i += 4) {
        ac0 = fmaf(h1s[w][i],     W2s[i * 64 + lane],       ac0);
        ac1 = fmaf(h1s[w][i + 1], W2s[(i + 1) * 64 + lane], ac1);
        ac2 = fmaf(h1s[w][i + 2], W2s[(i + 2) * 64 + lane], ac2);
        ac3 = fmaf(h1s[w][i + 3], W2s[(i + 3) * 64 + lane], ac3);
      }
      h2s[w][lane] = fmaxf((ac0 + ac1) + (ac2 + ac3), 0.f);
      __syncthreads();
      float bc0 = bias3, bc1 = 0.f, bc2 = 0.f, bc3 = 0.f;
      #pragma unroll
      for (int i = 0; i < 64; i += 4) {
        bc0 = fmaf(h2s[w][i],     W3s[i * 64 + lane],       bc0);
        bc1 = fmaf(h2s[w][i + 1], W3s[(i + 1) * 64 + lane], bc1);
        bc2 = fmaf(h2s[w][i + 2], W3s[(i + 2) * 64 + lane], bc2);
        bc3 = fmaf(h2s[w][i + 3], W3s[(i + 3) * 64 + lane], bc3);
      }
      vmax = fmaxf(vmax, fmaxf((bc0 + bc1) + (bc2 + bc3), 0.f));
    }
    vert[n * 64 + lane] = vmax;
  }
}

// ---------------- K7: global max over N per batch ----------------
__global__ void k_gmax(const float* __restrict__ vert, float* __restrict__ g) {
  __shared__ float red[4][64];
  int b = blockIdx.x >> 4, chunk = blockIdx.x & 15;
  int sub = threadIdx.x >> 6, o = threadIdx.x & 63;
  float vm = 0.f;
  for (int j = 0; j < 64; ++j) {
    int r = chunk * 256 + j * 4 + sub;
    vm = fmaxf(vm, vert[(b * NN + r) * 64 + o]);
  }
  red[sub][o] = vm;
  __syncthreads();
  if (sub == 0) {
    float mm = fmaxf(fmaxf(red[0][o], red[1][o]), fmaxf(red[2][o], red[3][o]));
    atomicMax((int*)&g[b * 64 + o], __float_as_int(mm));  // vert >= 0
  }
}

// ---------------- K7b: gb[b] = g[b] @ Wg_bottom + bg ----------------
__global__ void k_gb(const float* __restrict__ g, const float* __restrict__ Wg,
                     const float* __restrict__ bg, float* __restrict__ gb) {
  int t = threadIdx.x;        // 512
  int b = t >> 6, o = t & 63;
  float acc = bg[o];
  #pragma unroll
  for (int i = 0; i < 64; ++i)
    acc = fmaf(g[b * 64 + i], Wg[(64 + i) * 64 + o], acc);
  gb[b * 64 + o] = acc;
}

// ---------------- K8: out = relu(vert @ Wg_top + gb[b]) ----------------
__global__ void k_final(const float* __restrict__ vert, const float* __restrict__ Wg,
                        const float* __restrict__ gb, float* __restrict__ out) {
  __shared__ float Wgs[64 * 64];
  int tid = threadIdx.x, w = tid >> 6, lane = tid & 63;
  for (int i = tid; i < 4096; i += 256) Wgs[i] = Wg[i];  // rows 0..63 contiguous
  __syncthreads();
  int gw = blockIdx.x * 4 + w;
  for (int j = 0; j < 4; ++j) {
    int n = gw + 8192 * j;
    int b = n >> 12;
    float vrow = vert[n * 64 + lane];
    float ac0 = gb[b * 64 + lane], ac1 = 0.f, ac2 = 0.f, ac3 = 0.f;
    #pragma unroll
    for (int i = 0; i < 64; i += 4) {
      ac0 = fmaf(__shfl(vrow, i),     Wgs[i * 64 + lane],       ac0);
      ac1 = fmaf(__shfl(vrow, i + 1), Wgs[(i + 1) * 64 + lane], ac1);
      ac2 = fmaf(__shfl(vrow, i + 2), Wgs[(i + 2) * 64 + lane], ac2);
      ac3 = fmaf(__shfl(vrow, i + 3), Wgs[(i + 3) * 64 + lane], ac3);
    }
    out[n * 64 + lane] = fmaxf((ac0 + ac1) + (ac2 + ac3), 0.f);
  }
}

extern "C" void kernel_launch(void* const* d_in, const int* in_sizes, int n_in,
                              void* d_out, int out_size, void* d_ws, size_t ws_size,
                              hipStream_t stream) {
  const float* x     = (const float*)d_in[0];
  const float* gamma = (const float*)d_in[1];
  const float* beta  = (const float*)d_in[2];
  const float* W1    = (const float*)d_in[3];
  const float* b1    = (const float*)d_in[4];
  const float* W2    = (const float*)d_in[5];
  const float* b2    = (const float*)d_in[6];
  const float* W3    = (const float*)d_in[7];
  const float* b3    = (const float*)d_in[8];
  const float* Wg    = (const float*)d_in[9];
  const float* bg    = (const float*)d_in[10];
  float* out = (float*)d_out;

  float* ws    = (float*)d_ws;
  float* stats = ws;                    // 128
  float* ss    = ws + 128;              // 128
  float* xn    = ws + 256;              // 2097152
  float* sq    = xn + 2097152;          // 32768
  int*   knn   = (int*)(sq + 32768);    // 327680 ints
  float* u     = (float*)(knn + 327680);// 4194304
  float* v     = u + 4194304;           // 4194304
  float* vert  = v + 4194304;           // 2097152
  float* g     = vert + 2097152;        // 512
  float* gb    = g + 512;               // 512

  hipMemsetAsync(stats, 0, 128 * sizeof(float), stream);
  hipMemsetAsync(g, 0, 512 * sizeof(float), stream);

  k_bn_stats<<<256, 256, 0, stream>>>(x, stats);
  k_bn_finalize<<<1, 64, 0, stream>>>(stats, gamma, beta, ss);
  k_normalize<<<8192, 256, 0, stream>>>(x, ss, xn, sq);
  k_knn<<<512, 256, 0, stream>>>(xn, sq, knn);
  k_uv<<<256, 256, 0, stream>>>(xn, W1, b1, u, v);
  k_edge<<<2048, 256, 0, stream>>>(u, v, knn, W2, b2, W3, b3, vert);
  k_gmax<<<128, 256, 0, stream>>>(vert, g);
  k_gb<<<1, 512, 0, stream>>>(g, Wg, bg, gb);
  k_final<<<2048, 256, 0, stream>>>(vert, Wg, gb, out);
}

// Round 3
// 1252.965 us; speedup vs baseline: 1.4986x; 1.4986x over previous
//
#include <hip/hip_runtime.h>
#include <float.h>

#define BB 8
#define NN 4096
#define DD 64
#define KNBR 10
#define ROWS (BB*NN)   // 32768

// ---------------- K1: BN stats (sum, sumsq per feature) ----------------
__global__ void k_bn_stats(const float* __restrict__ x, float* __restrict__ stats) {
  __shared__ float ls[2][4][64];
  int d = threadIdx.x & 63;
  int g = threadIdx.x >> 6;
  float s = 0.f, s2 = 0.f;
  for (int r = blockIdx.x * 4 + g; r < ROWS; r += gridDim.x * 4) {
    float val = x[r * 64 + d];
    s += val;
    s2 = fmaf(val, val, s2);
  }
  ls[0][g][d] = s;
  ls[1][g][d] = s2;
  __syncthreads();
  if (g == 0) {
    atomicAdd(&stats[d],      ls[0][0][d] + ls[0][1][d] + ls[0][2][d] + ls[0][3][d]);
    atomicAdd(&stats[64 + d], ls[1][0][d] + ls[1][1][d] + ls[1][2][d] + ls[1][3][d]);
  }
}

// ---------------- K2: finalize scale/shift ----------------
__global__ void k_bn_finalize(const float* __restrict__ stats,
                              const float* __restrict__ gamma,
                              const float* __restrict__ beta,
                              float* __restrict__ ss) {
  int d = threadIdx.x;  // 64 threads
  const float inv = 1.f / 32768.f;
  float mu  = stats[d] * inv;
  float var = stats[64 + d] * inv - mu * mu;
  float sc  = gamma[d] / sqrtf(var + 1e-5f);
  ss[d]      = sc;
  ss[64 + d] = beta[d] - mu * sc;
}

// ---------------- K3: normalize + per-row sum of squares ----------------
__global__ void k_normalize(const float* __restrict__ x, const float* __restrict__ ss,
                            float* __restrict__ xn, float* __restrict__ sq) {
  int row = blockIdx.x * 4 + (threadIdx.x >> 6);
  int d = threadIdx.x & 63;
  float val = fmaf(x[row * 64 + d], ss[d], ss[64 + d]);
  xn[row * 64 + d] = val;
  float p = val * val;
  #pragma unroll
  for (int off = 32; off > 0; off >>= 1) p += __shfl_xor(p, off);
  if (d == 0) sq[row] = p;
}

// ---------------- K4: KNN (top-10 smallest dist per row) ----------------
// block = 256 thr = 4 waves; block owns 64 rows (lane = row); wave w owns
// m-range [w*1024,(w+1)*1024) in 16 LDS-staged tiles of 64. dist ordering
// uses sq[m] - 2*dot (sq[row] constant per row -> same order as reference).
// knn[] stores GLOBAL row indices (b*NN + m).
__global__ __launch_bounds__(256, 2) void k_knn(const float* __restrict__ xn,
                                                const float* __restrict__ sq,
                                                int* __restrict__ knn) {
  __shared__ float smem[16384];   // 64 KB: 4 tiles of [64][64]
  __shared__ float sqs[4][64];
  const int tid = threadIdx.x;
  const int w = tid >> 6, lane = tid & 63;
  const int b = blockIdx.x >> 6;
  const int rowbase = (blockIdx.x & 63) << 6;
  const float* xb = xn + b * NN * 64;

  // cache this lane's row in registers
  float4 rr[16];
  {
    const float4* rp = (const float4*)(xb + (rowbase + lane) * 64);
    #pragma unroll
    for (int i = 0; i < 16; ++i) rr[i] = rp[i];
  }

  float bd[10]; int bi[10];
  #pragma unroll
  for (int i = 0; i < 10; ++i) { bd[i] = FLT_MAX; bi[i] = 0; }

  float* tile = smem + w * 4096;
  for (int t = 0; t < 16; ++t) {
    const int mbase = (w * 16 + t) << 6;
    {
      const float4* s4 = (const float4*)(xb + mbase * 64);
      float4* d4 = (float4*)tile;
      #pragma unroll
      for (int i = 0; i < 16; ++i) d4[i * 64 + lane] = s4[i * 64 + lane];
      sqs[w][lane] = sq[b * NN + mbase + lane];
    }
    __syncthreads();
    #pragma unroll 1
    for (int m = 0; m < 64; ++m) {
      const float4* Mr = (const float4*)(tile + m * 64);
      float a0 = 0.f, a1 = 0.f, a2 = 0.f, a3 = 0.f;
      #pragma unroll
      for (int i = 0; i < 16; i += 4) {
        float4 q0 = Mr[i], q1 = Mr[i + 1], q2 = Mr[i + 2], q3 = Mr[i + 3];
        a0 = fmaf(rr[i].x, q0.x, fmaf(rr[i].y, q0.y, fmaf(rr[i].z, q0.z, fmaf(rr[i].w, q0.w, a0))));
        a1 = fmaf(rr[i+1].x, q1.x, fmaf(rr[i+1].y, q1.y, fmaf(rr[i+1].z, q1.z, fmaf(rr[i+1].w, q1.w, a1))));
        a2 = fmaf(rr[i+2].x, q2.x, fmaf(rr[i+2].y, q2.y, fmaf(rr[i+2].z, q2.z, fmaf(rr[i+2].w, q2.w, a2))));
        a3 = fmaf(rr[i+3].x, q3.x, fmaf(rr[i+3].y, q3.y, fmaf(rr[i+3].z, q3.z, fmaf(rr[i+3].w, q3.w, a3))));
      }
      float dist = fmaf(-2.f, (a0 + a1) + (a2 + a3), sqs[w][m]);
      if (dist < bd[9]) {       // rare: sorted-insert ladder, static indices only
        float cd = dist; int ci = mbase + m;
        #pragma unroll
        for (int j = 0; j < 10; ++j) {
          bool sw = cd < bd[j];
          float tf = bd[j]; int ti = bi[j];
          bd[j] = sw ? cd : tf; bi[j] = sw ? ci : ti;
          cd = sw ? tf : cd;    ci = sw ? ti : ci;
        }
      }
    }
    __syncthreads();
  }

  // merge the 4 per-wave top-10 lists per row
  float* md = smem;                   // [4][64][10] dists (reuses tile space)
  int*   mi = (int*)(smem + 2560);    // [4][64][10] indices
  #pragma unroll
  for (int i = 0; i < 10; ++i) {
    md[(w * 64 + lane) * 10 + i] = bd[i];
    mi[(w * 64 + lane) * 10 + i] = bi[i];
  }
  __syncthreads();
  if (tid < 64) {
    float fd[10]; int fi[10];
    #pragma unroll
    for (int i = 0; i < 10; ++i) { fd[i] = FLT_MAX; fi[i] = 0; }
    for (int w2 = 0; w2 < 4; ++w2) {
      for (int kk = 0; kk < 10; ++kk) {
        float dd = md[(w2 * 64 + tid) * 10 + kk];
        int   ii = mi[(w2 * 64 + tid) * 10 + kk];
        if (dd < fd[9]) {
          float cd = dd; int ci = ii;
          #pragma unroll
          for (int j = 0; j < 10; ++j) {
            bool sw = cd < fd[j];
            float tf = fd[j]; int ti = fi[j];
            fd[j] = sw ? cd : tf; fi[j] = sw ? ci : ti;
            cd = sw ? tf : cd;    ci = sw ? ti : ci;
          }
        }
      }
    }
    #pragma unroll
    for (int kk = 0; kk < 10; ++kk)
      knn[(b * NN + rowbase + tid) * KNBR + kk] = b * NN + fi[kk];  // GLOBAL index
  }
}

// ---------------- K5: U/V precompute (layer-1 folded per point) ----------------
// U[n][o] = sum_d xn[n][d]*(W1[d][o]+W1[64+d][o]) + b1[o]
// V[n][o] = sum_d xn[n][d]*W1[64+d][o]      -> h1(edge n,m) = relu(U[n]-V[m])
// v2: weight column register-cached per thread; xn tile staged in LDS.
// threads 0-127 -> U columns, threads 128-255 -> V columns. 64 rows/block.
__global__ void k_uv(const float* __restrict__ xn, const float* __restrict__ W1,
                     const float* __restrict__ b1, float* __restrict__ u,
                     float* __restrict__ v) {
  __shared__ float xs[64 * 64];   // 16 KB
  const int tid = threadIdx.x;
  const int o = tid & 127;
  const bool isU = tid < 128;
  const int rowbase = blockIdx.x * 64;

  // register-cache this thread's weight column (static indices -> VGPRs)
  float wreg[64];
  #pragma unroll
  for (int d = 0; d < 64; ++d) {
    float bw = W1[(64 + d) * 128 + o];
    wreg[d] = isU ? (W1[d * 128 + o] + bw) : bw;
  }
  const float bb = isU ? b1[o] : 0.f;
  float* __restrict__ dst = isU ? u : v;

  // stage 64 rows coalesced
  {
    const float4* s4 = (const float4*)(xn + rowbase * 64);
    float4* d4 = (float4*)xs;
    #pragma unroll
    for (int i = 0; i < 4; ++i) d4[tid + 256 * i] = s4[tid + 256 * i];
  }
  __syncthreads();

  for (int r = 0; r < 64; ++r) {
    const float4* xr = (const float4*)(xs + r * 64);
    float a0 = bb, a1 = 0.f, a2 = 0.f, a3 = 0.f;
    #pragma unroll
    for (int q = 0; q < 16; ++q) {
      float4 xv = xr[q];
      a0 = fmaf(xv.x, wreg[4 * q + 0], a0);
      a1 = fmaf(xv.y, wreg[4 * q + 1], a1);
      a2 = fmaf(xv.z, wreg[4 * q + 2], a2);
      a3 = fmaf(xv.w, wreg[4 * q + 3], a3);
    }
    dst[(rowbase + r) * 128 + o] = (a0 + a1) + (a2 + a3);
  }
}

// ---------------- K6: edge MLP (h1->h2->h3) + max over K ----------------
__global__ __launch_bounds__(256, 3) void k_edge(const float* __restrict__ u,
                                                 const float* __restrict__ v,
                                                 const int* __restrict__ knn,
                                                 const float* __restrict__ W2,
                                                 const float* __restrict__ b2,
                                                 const float* __restrict__ W3,
                                                 const float* __restrict__ b3,
                                                 float* __restrict__ vert) {
  __shared__ float W2s[128 * 64];
  __shared__ float W3s[64 * 64];
  __shared__ float h1s[4][128];
  __shared__ float h2s[4][64];
  int tid = threadIdx.x, w = tid >> 6, lane = tid & 63;
  for (int i = tid; i < 128 * 64; i += 256) W2s[i] = W2[i];
  for (int i = tid; i < 64 * 64; i += 256)  W3s[i] = W3[i];
  __syncthreads();
  float bias2 = b2[lane], bias3 = b3[lane];
  int gw = blockIdx.x * 4 + w;
  for (int j = 0; j < 4; ++j) {
    int n = gw + 8192 * j;
    float u0 = u[n * 128 + lane], u1 = u[n * 128 + 64 + lane];
    float vmax = 0.f;
    for (int k = 0; k < KNBR; ++k) {
      int m = knn[n * KNBR + k];
      h1s[w][lane]      = fmaxf(u0 - v[m * 128 + lane], 0.f);
      h1s[w][lane + 64] = fmaxf(u1 - v[m * 128 + 64 + lane], 0.f);
      __syncthreads();
      float ac0 = bias2, ac1 = 0.f, ac2 = 0.f, ac3 = 0.f;
      #pragma unroll
      for (int i = 0; i < 128; i += 4) {
        ac0 = fmaf(h1s[w][i],     W2s[i * 64 + lane],       ac0);
        ac1 = fmaf(h1s[w][i + 1], W2s[(i + 1) * 64 + lane], ac1);
        ac2 = fmaf(h1s[w][i + 2], W2s[(i + 2) * 64 + lane], ac2);
        ac3 = fmaf(h1s[w][i + 3], W2s[(i + 3) * 64 + lane], ac3);
      }
      h2s[w][lane] = fmaxf((ac0 + ac1) + (ac2 + ac3), 0.f);
      __syncthreads();
      float bc0 = bias3, bc1 = 0.f, bc2 = 0.f, bc3 = 0.f;
      #pragma unroll
      for (int i = 0; i < 64; i += 4) {
        bc0 = fmaf(h2s[w][i],     W3s[i * 64 + lane],       bc0);
        bc1 = fmaf(h2s[w][i + 1], W3s[(i + 1) * 64 + lane], bc1);
        bc2 = fmaf(h2s[w][i + 2], W3s[(i + 2) * 64 + lane], bc2);
        bc3 = fmaf(h2s[w][i + 3], W3s[(i + 3) * 64 + lane], bc3);
      }
      vmax = fmaxf(vmax, fmaxf((bc0 + bc1) + (bc2 + bc3), 0.f));
    }
    vert[n * 64 + lane] = vmax;
  }
}

// ---------------- K7: global max over N per batch ----------------
__global__ void k_gmax(const float* __restrict__ vert, float* __restrict__ g) {
  __shared__ float red[4][64];
  int b = blockIdx.x >> 4, chunk = blockIdx.x & 15;
  int sub = threadIdx.x >> 6, o = threadIdx.x & 63;
  float vm = 0.f;
  for (int j = 0; j < 64; ++j) {
    int r = chunk * 256 + j * 4 + sub;
    vm = fmaxf(vm, vert[(b * NN + r) * 64 + o]);
  }
  red[sub][o] = vm;
  __syncthreads();
  if (sub == 0) {
    float mm = fmaxf(fmaxf(red[0][o], red[1][o]), fmaxf(red[2][o], red[3][o]));
    atomicMax((int*)&g[b * 64 + o], __float_as_int(mm));  // vert >= 0
  }
}

// ---------------- K7b: gb[b] = g[b] @ Wg_bottom + bg ----------------
__global__ void k_gb(const float* __restrict__ g, const float* __restrict__ Wg,
                     const float* __restrict__ bg, float* __restrict__ gb) {
  int t = threadIdx.x;        // 512
  int b = t >> 6, o = t & 63;
  float acc = bg[o];
  #pragma unroll
  for (int i = 0; i < 64; ++i)
    acc = fmaf(g[b * 64 + i], Wg[(64 + i) * 64 + o], acc);
  gb[b * 64 + o] = acc;
}

// ---------------- K8: out = relu(vert @ Wg_top + gb[b]) ----------------
__global__ void k_final(const float* __restrict__ vert, const float* __restrict__ Wg,
                        const float* __restrict__ gb, float* __restrict__ out) {
  __shared__ float Wgs[64 * 64];
  int tid = threadIdx.x, w = tid >> 6, lane = tid & 63;
  for (int i = tid; i < 4096; i += 256) Wgs[i] = Wg[i];  // rows 0..63 contiguous
  __syncthreads();
  int gw = blockIdx.x * 4 + w;
  for (int j = 0; j < 4; ++j) {
    int n = gw + 8192 * j;
    int b = n >> 12;
    float vrow = vert[n * 64 + lane];
    float ac0 = gb[b * 64 + lane], ac1 = 0.f, ac2 = 0.f, ac3 = 0.f;
    #pragma unroll
    for (int i = 0; i < 64; i += 4) {
      ac0 = fmaf(__shfl(vrow, i),     Wgs[i * 64 + lane],       ac0);
      ac1 = fmaf(__shfl(vrow, i + 1), Wgs[(i + 1) * 64 + lane], ac1);
      ac2 = fmaf(__shfl(vrow, i + 2), Wgs[(i + 2) * 64 + lane], ac2);
      ac3 = fmaf(__shfl(vrow, i + 3), Wgs[(i + 3) * 64 + lane], ac3);
    }
    out[n * 64 + lane] = fmaxf((ac0 + ac1) + (ac2 + ac3), 0.f);
  }
}

extern "C" void kernel_launch(void* const* d_in, const int* in_sizes, int n_in,
                              void* d_out, int out_size, void* d_ws, size_t ws_size,
                              hipStream_t stream) {
  const float* x     = (const float*)d_in[0];
  const float* gamma = (const float*)d_in[1];
  const float* beta  = (const float*)d_in[2];
  const float* W1    = (const float*)d_in[3];
  const float* b1    = (const float*)d_in[4];
  const float* W2    = (const float*)d_in[5];
  const float* b2    = (const float*)d_in[6];
  const float* W3    = (const float*)d_in[7];
  const float* b3    = (const float*)d_in[8];
  const float* Wg    = (const float*)d_in[9];
  const float* bg    = (const float*)d_in[10];
  float* out = (float*)d_out;

  float* ws    = (float*)d_ws;
  float* stats = ws;                    // 128
  float* ss    = ws + 128;              // 128
  float* xn    = ws + 256;              // 2097152
  float* sq    = xn + 2097152;          // 32768
  int*   knn   = (int*)(sq + 32768);    // 327680 ints
  float* u     = (float*)(knn + 327680);// 4194304
  float* v     = u + 4194304;           // 4194304
  float* vert  = v + 4194304;           // 2097152
  float* g     = vert + 2097152;        // 512
  float* gb    = g + 512;               // 512

  hipMemsetAsync(stats, 0, 128 * sizeof(float), stream);
  hipMemsetAsync(g, 0, 512 * sizeof(float), stream);

  k_bn_stats<<<256, 256, 0, stream>>>(x, stats);
  k_bn_finalize<<<1, 64, 0, stream>>>(stats, gamma, beta, ss);
  k_normalize<<<8192, 256, 0, stream>>>(x, ss, xn, sq);
  k_knn<<<512, 256, 0, stream>>>(xn, sq, knn);
  k_uv<<<512, 256, 0, stream>>>(xn, W1, b1, u, v);
  k_edge<<<2048, 256, 0, stream>>>(u, v, knn, W2, b2, W3, b3, vert);
  k_gmax<<<128, 256, 0, stream>>>(vert, g);
  k_gb<<<1, 512, 0, stream>>>(g, Wg, bg, gb);
  k_final<<<2048, 256, 0, stream>>>(vert, Wg, gb, out);
}

// Round 4
// 894.196 us; speedup vs baseline: 2.0998x; 1.4012x over previous
//
#include <hip/hip_runtime.h>
#include <hip/hip_fp16.h>
#include <float.h>

#define BB 8
#define NN 4096
#define DD 64
#define KNBR 10
#define ROWS (BB*NN)   // 32768

typedef _Float16 f16x8 __attribute__((ext_vector_type(8)));
typedef float f32x4 __attribute__((ext_vector_type(4)));

// ---------------- K1: BN stats (sum, sumsq per feature) ----------------
__global__ void k_bn_stats(const float* __restrict__ x, float* __restrict__ stats) {
  __shared__ float ls[2][4][64];
  int d = threadIdx.x & 63;
  int g = threadIdx.x >> 6;
  float s = 0.f, s2 = 0.f;
  for (int r = blockIdx.x * 4 + g; r < ROWS; r += gridDim.x * 4) {
    float val = x[r * 64 + d];
    s += val;
    s2 = fmaf(val, val, s2);
  }
  ls[0][g][d] = s;
  ls[1][g][d] = s2;
  __syncthreads();
  if (g == 0) {
    atomicAdd(&stats[d],      ls[0][0][d] + ls[0][1][d] + ls[0][2][d] + ls[0][3][d]);
    atomicAdd(&stats[64 + d], ls[1][0][d] + ls[1][1][d] + ls[1][2][d] + ls[1][3][d]);
  }
}

// ---------------- K2: finalize scale/shift ----------------
__global__ void k_bn_finalize(const float* __restrict__ stats,
                              const float* __restrict__ gamma,
                              const float* __restrict__ beta,
                              float* __restrict__ ss) {
  int d = threadIdx.x;  // 64 threads
  const float inv = 1.f / 32768.f;
  float mu  = stats[d] * inv;
  float var = stats[64 + d] * inv - mu * mu;
  float sc  = gamma[d] / sqrtf(var + 1e-5f);
  ss[d]      = sc;
  ss[64 + d] = beta[d] - mu * sc;
}

// ---------------- K3: normalize + row sumsq + f16 hi/lo planes ----------------
__global__ void k_normalize(const float* __restrict__ x, const float* __restrict__ ss,
                            float* __restrict__ xn, float* __restrict__ sq,
                            _Float16* __restrict__ xh, _Float16* __restrict__ xl) {
  int row = blockIdx.x * 4 + (threadIdx.x >> 6);
  int d = threadIdx.x & 63;
  int idx = row * 64 + d;
  float val = fmaf(x[idx], ss[d], ss[64 + d]);
  xn[idx] = val;
  _Float16 h = (_Float16)val;
  _Float16 l = (_Float16)(val - (float)h);
  xh[idx] = h;
  xl[idx] = l;
  float p = val * val;
  #pragma unroll
  for (int off = 32; off > 0; off >>= 1) p += __shfl_xor(p, off);
  if (d == 0) sq[row] = p;
}

// ---------------- K4: KNN via compensated-f16 MFMA distance tiles ----------------
// Block = 4 waves, 64 rows. Wave w owns m-tiles {4t+w}*32, t=0..31 (disjoint
// 1024-m stream -> ladder amortizes). Per tile: stage 32 m-rows hi/lo f16 into
// per-wave XOR-swizzled LDS (barrier-free), 48 MFMA (3 compensation passes),
// dist tile -> pad-33 LDS, lane=row ladder scan. dist key = sq[m]-2*dot.
__global__ __launch_bounds__(256, 2) void k_knn(const _Float16* __restrict__ xh,
                                                const _Float16* __restrict__ xl,
                                                const float* __restrict__ sq,
                                                int* __restrict__ knn) {
  __shared__ __align__(16) float lds[16640];   // 66560 B = 4 waves x 16640 B
  const int tid = threadIdx.x;
  const int w = tid >> 6, lane = tid & 63;
  const int l15 = lane & 15, lg = lane >> 4;
  const int b = blockIdx.x >> 6;
  const int rowbase = (blockIdx.x & 63) << 6;
  const int bN = b * NN;
  const _Float16* __restrict__ xhb = xh + (size_t)bN * 64;
  const _Float16* __restrict__ xlb = xl + (size_t)bN * 64;

  char* wbase = (char*)lds + w * 16640;
  char* Bhi = wbase;                    // 32 rows x 64 f16, XOR-swizzled (4096 B)
  char* Blo = wbase + 4096;             // 4096 B
  float* Dw = (float*)(wbase + 8192);   // [64][33] floats (8448 B)

  // A fragments for the block's 64 rows (persistent in VGPRs)
  f16x8 Ah[4][2], Al[4][2];
  #pragma unroll
  for (int mt = 0; mt < 4; ++mt) {
    #pragma unroll
    for (int ks = 0; ks < 2; ++ks) {
      int r = rowbase + mt * 16 + l15;
      Ah[mt][ks] = *(const f16x8*)(xhb + r * 64 + ks * 32 + lg * 8);
      Al[mt][ks] = *(const f16x8*)(xlb + r * 64 + ks * 32 + lg * 8);
    }
  }

  float bd[10]; int bi[10];
  #pragma unroll
  for (int i = 0; i < 10; ++i) { bd[i] = FLT_MAX; bi[i] = 0; }

  // staging chunk coords: chunk c = i*64+lane of 256 (row=c>>3, cc=c&7)
  int srow[4], scc[4];
  #pragma unroll
  for (int i = 0; i < 4; ++i) { int c = i * 64 + lane; srow[i] = c >> 3; scc[i] = c & 7; }

  // preload tile 0
  f16x8 sh[4], sl[4];
  {
    int mb0 = w * 32;
    #pragma unroll
    for (int i = 0; i < 4; ++i) {
      sh[i] = *(const f16x8*)(xhb + (mb0 + srow[i]) * 64 + scc[i] * 8);
      sl[i] = *(const f16x8*)(xlb + (mb0 + srow[i]) * 64 + scc[i] * 8);
    }
  }

  float* Drow = Dw + lane * 33;

  #pragma unroll 1
  for (int t = 0; t < 32; ++t) {
    const int mb = (t * 4 + w) * 32;
    const int mb2 = (t < 31) ? ((t + 1) * 4 + w) * 32 : mb;
    float sqv0 = sq[bN + mb + l15];
    float sqv1 = sq[bN + mb + 16 + l15];
    // write staged regs -> swizzled LDS (own region, no barrier)
    #pragma unroll
    for (int i = 0; i < 4; ++i) {
      int off = srow[i] * 128 + 16 * (scc[i] ^ (srow[i] & 7));
      *(f16x8*)(Bhi + off) = sh[i];
      *(f16x8*)(Blo + off) = sl[i];
    }
    // prefetch next tile (flies under MFMA+selection)
    #pragma unroll
    for (int i = 0; i < 4; ++i) {
      sh[i] = *(const f16x8*)(xhb + (mb2 + srow[i]) * 64 + scc[i] * 8);
      sl[i] = *(const f16x8*)(xlb + (mb2 + srow[i]) * 64 + scc[i] * 8);
    }
    // B fragments (swizzled read, 2-way max)
    f16x8 Bh[2][2], Bl[2][2];
    #pragma unroll
    for (int nt = 0; nt < 2; ++nt) {
      #pragma unroll
      for (int ks = 0; ks < 2; ++ks) {
        int rr2 = nt * 16 + l15;
        int off = rr2 * 128 + 16 * ((ks * 4 + lg) ^ (rr2 & 7));
        Bh[nt][ks] = *(const f16x8*)(Bhi + off);
        Bl[nt][ks] = *(const f16x8*)(Blo + off);
      }
    }
    // 48 MFMA: hi*hi + hi*lo + lo*hi (fp32 acc)
    #pragma unroll
    for (int mt = 0; mt < 4; ++mt) {
      f32x4 a0 = {0.f, 0.f, 0.f, 0.f}, a1 = {0.f, 0.f, 0.f, 0.f};
      #pragma unroll
      for (int ks = 0; ks < 2; ++ks) {
        a0 = __builtin_amdgcn_mfma_f32_16x16x32_f16(Ah[mt][ks], Bh[0][ks], a0, 0, 0, 0);
        a1 = __builtin_amdgcn_mfma_f32_16x16x32_f16(Ah[mt][ks], Bh[1][ks], a1, 0, 0, 0);
        a0 = __builtin_amdgcn_mfma_f32_16x16x32_f16(Ah[mt][ks], Bl[0][ks], a0, 0, 0, 0);
        a1 = __builtin_amdgcn_mfma_f32_16x16x32_f16(Ah[mt][ks], Bl[1][ks], a1, 0, 0, 0);
        a0 = __builtin_amdgcn_mfma_f32_16x16x32_f16(Al[mt][ks], Bh[0][ks], a0, 0, 0, 0);
        a1 = __builtin_amdgcn_mfma_f32_16x16x32_f16(Al[mt][ks], Bh[1][ks], a1, 0, 0, 0);
      }
      // C layout: col=lane&15, row=(lane>>4)*4+reg  ->  D[row][m] pad 33
      int rw = mt * 16 + lg * 4;
      #pragma unroll
      for (int r2 = 0; r2 < 4; ++r2) {
        Dw[(rw + r2) * 33 + l15]      = fmaf(-2.f, a0[r2], sqv0);
        Dw[(rw + r2) * 33 + 16 + l15] = fmaf(-2.f, a1[r2], sqv1);
      }
    }
    // selection: lane = row, scan 32 m's (bank-conflict-free, stride 33)
    #pragma unroll 4
    for (int mm = 0; mm < 32; ++mm) {
      float dv = Drow[mm];
      if (dv < bd[9]) {
        float cd = dv; int ci = bN + mb + mm;   // GLOBAL row index
        #pragma unroll
        for (int j = 0; j < 10; ++j) {
          bool swp = cd < bd[j];
          float tf = bd[j]; int ti = bi[j];
          bd[j] = swp ? cd : tf; bi[j] = swp ? ci : ti;
          cd = swp ? tf : cd;    ci = swp ? ti : ci;
        }
      }
    }
  }

  // merge the 4 per-wave top-10 lists per row
  __syncthreads();
  float* md = lds;                   // [4][64][10] dists
  int*   mi = (int*)(lds + 2560);    // [4][64][10] indices
  #pragma unroll
  for (int i = 0; i < 10; ++i) {
    md[(w * 64 + lane) * 10 + i] = bd[i];
    mi[(w * 64 + lane) * 10 + i] = bi[i];
  }
  __syncthreads();
  if (tid < 64) {
    float fd[10]; int fi[10];
    #pragma unroll
    for (int i = 0; i < 10; ++i) { fd[i] = FLT_MAX; fi[i] = 0; }
    for (int w2 = 0; w2 < 4; ++w2) {
      for (int kk = 0; kk < 10; ++kk) {
        float dd2 = md[(w2 * 64 + tid) * 10 + kk];
        int   ii2 = mi[(w2 * 64 + tid) * 10 + kk];
        if (dd2 < fd[9]) {
          float cd = dd2; int ci = ii2;
          #pragma unroll
          for (int j = 0; j < 10; ++j) {
            bool swp = cd < fd[j];
            float tf = fd[j]; int ti = fi[j];
            fd[j] = swp ? cd : tf; fi[j] = swp ? ci : ti;
            cd = swp ? tf : cd;    ci = swp ? ti : ci;
          }
        }
      }
    }
    #pragma unroll
    for (int kk = 0; kk < 10; ++kk)
      knn[(bN + rowbase + tid) * KNBR + kk] = fi[kk];  // already global
  }
}

// ---------------- K5: U/V precompute (layer-1 folded per point) ----------------
__global__ void k_uv(const float* __restrict__ xn, const float* __restrict__ W1,
                     const float* __restrict__ b1, float* __restrict__ u,
                     float* __restrict__ v) {
  __shared__ float xs[64 * 64];   // 16 KB
  const int tid = threadIdx.x;
  const int o = tid & 127;
  const bool isU = tid < 128;
  const int rowbase = blockIdx.x * 64;

  float wreg[64];
  #pragma unroll
  for (int d = 0; d < 64; ++d) {
    float bw = W1[(64 + d) * 128 + o];
    wreg[d] = isU ? (W1[d * 128 + o] + bw) : bw;
  }
  const float bb = isU ? b1[o] : 0.f;
  float* __restrict__ dst = isU ? u : v;

  {
    const float4* s4 = (const float4*)(xn + rowbase * 64);
    float4* d4 = (float4*)xs;
    #pragma unroll
    for (int i = 0; i < 4; ++i) d4[tid + 256 * i] = s4[tid + 256 * i];
  }
  __syncthreads();

  for (int r = 0; r < 64; ++r) {
    const float4* xr = (const float4*)(xs + r * 64);
    float a0 = bb, a1 = 0.f, a2 = 0.f, a3 = 0.f;
    #pragma unroll
    for (int q = 0; q < 16; ++q) {
      float4 xv = xr[q];
      a0 = fmaf(xv.x, wreg[4 * q + 0], a0);
      a1 = fmaf(xv.y, wreg[4 * q + 1], a1);
      a2 = fmaf(xv.z, wreg[4 * q + 2], a2);
      a3 = fmaf(xv.w, wreg[4 * q + 3], a3);
    }
    dst[(rowbase + r) * 128 + o] = (a0 + a1) + (a2 + a3);
  }
}

// ---------------- K6: edge MLP (h1->h2->h3) + max over K ----------------
__global__ __launch_bounds__(256, 3) void k_edge(const float* __restrict__ u,
                                                 const float* __restrict__ v,
                                                 const int* __restrict__ knn,
                                                 const float* __restrict__ W2,
                                                 const float* __restrict__ b2,
                                                 const float* __restrict__ W3,
                                                 const float* __restrict__ b3,
                                                 float* __restrict__ vert) {
  __shared__ float W2s[128 * 64];
  __shared__ float W3s[64 * 64];
  __shared__ float h1s[4][128];
  __shared__ float h2s[4][64];
  int tid = threadIdx.x, w = tid >> 6, lane = tid & 63;
  for (int i = tid; i < 128 * 64; i += 256) W2s[i] = W2[i];
  for (int i = tid; i < 64 * 64; i += 256)  W3s[i] = W3[i];
  __syncthreads();
  float bias2 = b2[lane], bias3 = b3[lane];
  int gw = blockIdx.x * 4 + w;
  for (int j = 0; j < 4; ++j) {
    int n = gw + 8192 * j;
    float u0 = u[n * 128 + lane], u1 = u[n * 128 + 64 + lane];
    float vmax = 0.f;
    for (int k = 0; k < KNBR; ++k) {
      int m = knn[n * KNBR + k];
      h1s[w][lane]      = fmaxf(u0 - v[m * 128 + lane], 0.f);
      h1s[w][lane + 64] = fmaxf(u1 - v[m * 128 + 64 + lane], 0.f);
      __syncthreads();
      float ac0 = bias2, ac1 = 0.f, ac2 = 0.f, ac3 = 0.f;
      #pragma unroll
      for (int i = 0; i < 128; i += 4) {
        ac0 = fmaf(h1s[w][i],     W2s[i * 64 + lane],       ac0);
        ac1 = fmaf(h1s[w][i + 1], W2s[(i + 1) * 64 + lane], ac1);
        ac2 = fmaf(h1s[w][i + 2], W2s[(i + 2) * 64 + lane], ac2);
        ac3 = fmaf(h1s[w][i + 3], W2s[(i + 3) * 64 + lane], ac3);
      }
      h2s[w][lane] = fmaxf((ac0 + ac1) + (ac2 + ac3), 0.f);
      __syncthreads();
      float bc0 = bias3, bc1 = 0.f, bc2 = 0.f, bc3 = 0.f;
      #pragma unroll
      for (int i = 0; i < 64; i += 4) {
        bc0 = fmaf(h2s[w][i],     W3s[i * 64 + lane],       bc0);
        bc1 = fmaf(h2s[w][i + 1], W3s[(i + 1) * 64 + lane], bc1);
        bc2 = fmaf(h2s[w][i + 2], W3s[(i + 2) * 64 + lane], bc2);
        bc3 = fmaf(h2s[w][i + 3], W3s[(i + 3) * 64 + lane], bc3);
      }
      vmax = fmaxf(vmax, fmaxf((bc0 + bc1) + (bc2 + bc3), 0.f));
    }
    vert[n * 64 + lane] = vmax;
  }
}

// ---------------- K7: global max over N per batch ----------------
__global__ void k_gmax(const float* __restrict__ vert, float* __restrict__ g) {
  __shared__ float red[4][64];
  int b = blockIdx.x >> 4, chunk = blockIdx.x & 15;
  int sub = threadIdx.x >> 6, o = threadIdx.x & 63;
  float vm = 0.f;
  for (int j = 0; j < 64; ++j) {
    int r = chunk * 256 + j * 4 + sub;
    vm = fmaxf(vm, vert[(b * NN + r) * 64 + o]);
  }
  red[sub][o] = vm;
  __syncthreads();
  if (sub == 0) {
    float mm = fmaxf(fmaxf(red[0][o], red[1][o]), fmaxf(red[2][o], red[3][o]));
    atomicMax((int*)&g[b * 64 + o], __float_as_int(mm));  // vert >= 0
  }
}

// ---------------- K7b: gb[b] = g[b] @ Wg_bottom + bg ----------------
__global__ void k_gb(const float* __restrict__ g, const float* __restrict__ Wg,
                     const float* __restrict__ bg, float* __restrict__ gb) {
  int t = threadIdx.x;        // 512
  int b = t >> 6, o = t & 63;
  float acc = bg[o];
  #pragma unroll
  for (int i = 0; i < 64; ++i)
    acc = fmaf(g[b * 64 + i], Wg[(64 + i) * 64 + o], acc);
  gb[b * 64 + o] = acc;
}

// ---------------- K8: out = relu(vert @ Wg_top + gb[b]) ----------------
__global__ void k_final(const float* __restrict__ vert, const float* __restrict__ Wg,
                        const float* __restrict__ gb, float* __restrict__ out) {
  __shared__ float Wgs[64 * 64];
  int tid = threadIdx.x, w = tid >> 6, lane = tid & 63;
  for (int i = tid; i < 4096; i += 256) Wgs[i] = Wg[i];
  __syncthreads();
  int gw = blockIdx.x * 4 + w;
  for (int j = 0; j < 4; ++j) {
    int n = gw + 8192 * j;
    int b = n >> 12;
    float vrow = vert[n * 64 + lane];
    float ac0 = gb[b * 64 + lane], ac1 = 0.f, ac2 = 0.f, ac3 = 0.f;
    #pragma unroll
    for (int i = 0; i < 64; i += 4) {
      ac0 = fmaf(__shfl(vrow, i),     Wgs[i * 64 + lane],       ac0);
      ac1 = fmaf(__shfl(vrow, i + 1), Wgs[(i + 1) * 64 + lane], ac1);
      ac2 = fmaf(__shfl(vrow, i + 2), Wgs[(i + 2) * 64 + lane], ac2);
      ac3 = fmaf(__shfl(vrow, i + 3), Wgs[(i + 3) * 64 + lane], ac3);
    }
    out[n * 64 + lane] = fmaxf((ac0 + ac1) + (ac2 + ac3), 0.f);
  }
}

extern "C" void kernel_launch(void* const* d_in, const int* in_sizes, int n_in,
                              void* d_out, int out_size, void* d_ws, size_t ws_size,
                              hipStream_t stream) {
  const float* x     = (const float*)d_in[0];
  const float* gamma = (const float*)d_in[1];
  const float* beta  = (const float*)d_in[2];
  const float* W1    = (const float*)d_in[3];
  const float* b1    = (const float*)d_in[4];
  const float* W2    = (const float*)d_in[5];
  const float* b2    = (const float*)d_in[6];
  const float* W3    = (const float*)d_in[7];
  const float* b3    = (const float*)d_in[8];
  const float* Wg    = (const float*)d_in[9];
  const float* bg    = (const float*)d_in[10];
  float* out = (float*)d_out;

  float* ws    = (float*)d_ws;
  float* stats = ws;                    // 128
  float* ss    = ws + 128;              // 128
  float* xn    = ws + 256;              // 2097152
  float* sq    = xn + 2097152;          // 32768
  int*   knn   = (int*)(sq + 32768);    // 327680 ints
  float* u     = (float*)(knn + 327680);// 4194304
  float* v     = u + 4194304;           // 4194304
  float* vert  = v + 4194304;           // 2097152
  float* g     = vert + 2097152;        // 512
  float* gb    = g + 512;               // 512
  _Float16* xh = (_Float16*)(gb + 512);             // 2097152 halfs (1 M floats)
  _Float16* xl = (_Float16*)(gb + 512 + 1048576);   // 2097152 halfs

  hipMemsetAsync(stats, 0, 128 * sizeof(float), stream);
  hipMemsetAsync(g, 0, 512 * sizeof(float), stream);

  k_bn_stats<<<256, 256, 0, stream>>>(x, stats);
  k_bn_finalize<<<1, 64, 0, stream>>>(stats, gamma, beta, ss);
  k_normalize<<<8192, 256, 0, stream>>>(x, ss, xn, sq, xh, xl);
  k_knn<<<512, 256, 0, stream>>>(xh, xl, sq, knn);
  k_uv<<<512, 256, 0, stream>>>(xn, W1, b1, u, v);
  k_edge<<<2048, 256, 0, stream>>>(u, v, knn, W2, b2, W3, b3, vert);
  k_gmax<<<128, 256, 0, stream>>>(vert, g);
  k_gb<<<1, 512, 0, stream>>>(g, Wg, bg, gb);
  k_final<<<2048, 256, 0, stream>>>(vert, Wg, gb, out);
}

// Round 5
// 474.876 us; speedup vs baseline: 3.9539x; 1.8830x over previous
//
#include <hip/hip_runtime.h>
#include <hip/hip_fp16.h>
#include <float.h>

#define BB 8
#define NN 4096
#define DD 64
#define KNBR 10
#define ROWS (BB*NN)   // 32768

typedef _Float16 f16x8 __attribute__((ext_vector_type(8)));
typedef float f32x4 __attribute__((ext_vector_type(4)));

// ---------------- K1: BN stats (sum, sumsq per feature) ----------------
__global__ void k_bn_stats(const float* __restrict__ x, float* __restrict__ stats) {
  __shared__ float ls[2][4][64];
  int d = threadIdx.x & 63;
  int g = threadIdx.x >> 6;
  float s = 0.f, s2 = 0.f;
  for (int r = blockIdx.x * 4 + g; r < ROWS; r += gridDim.x * 4) {
    float val = x[r * 64 + d];
    s += val;
    s2 = fmaf(val, val, s2);
  }
  ls[0][g][d] = s;
  ls[1][g][d] = s2;
  __syncthreads();
  if (g == 0) {
    atomicAdd(&stats[d],      ls[0][0][d] + ls[0][1][d] + ls[0][2][d] + ls[0][3][d]);
    atomicAdd(&stats[64 + d], ls[1][0][d] + ls[1][1][d] + ls[1][2][d] + ls[1][3][d]);
  }
}

// ---------------- K2: finalize scale/shift ----------------
__global__ void k_bn_finalize(const float* __restrict__ stats,
                              const float* __restrict__ gamma,
                              const float* __restrict__ beta,
                              float* __restrict__ ss) {
  int d = threadIdx.x;  // 64 threads
  const float inv = 1.f / 32768.f;
  float mu  = stats[d] * inv;
  float var = stats[64 + d] * inv - mu * mu;
  float sc  = gamma[d] / sqrtf(var + 1e-5f);
  ss[d]      = sc;
  ss[64 + d] = beta[d] - mu * sc;
}

// ---------------- K3: normalize + row sumsq + f16 hi/lo planes ----------------
__global__ void k_normalize(const float* __restrict__ x, const float* __restrict__ ss,
                            float* __restrict__ xn, float* __restrict__ sq,
                            _Float16* __restrict__ xh, _Float16* __restrict__ xl) {
  int row = blockIdx.x * 4 + (threadIdx.x >> 6);
  int d = threadIdx.x & 63;
  int idx = row * 64 + d;
  float val = fmaf(x[idx], ss[d], ss[64 + d]);
  xn[idx] = val;
  _Float16 h = (_Float16)val;
  _Float16 l = (_Float16)(val - (float)h);
  xh[idx] = h;
  xl[idx] = l;
  float p = val * val;
  #pragma unroll
  for (int off = 32; off > 0; off >>= 1) p += __shfl_xor(p, off);
  if (d == 0) sq[row] = p;
}

// ---------------- K4: KNN via compensated-f16 MFMA distance tiles ----------------
__global__ __launch_bounds__(256, 2) void k_knn(const _Float16* __restrict__ xh,
                                                const _Float16* __restrict__ xl,
                                                const float* __restrict__ sq,
                                                int* __restrict__ knn) {
  __shared__ __align__(16) float lds[16640];   // 66560 B = 4 waves x 16640 B
  const int tid = threadIdx.x;
  const int w = tid >> 6, lane = tid & 63;
  const int l15 = lane & 15, lg = lane >> 4;
  const int b = blockIdx.x >> 6;
  const int rowbase = (blockIdx.x & 63) << 6;
  const int bN = b * NN;
  const _Float16* __restrict__ xhb = xh + (size_t)bN * 64;
  const _Float16* __restrict__ xlb = xl + (size_t)bN * 64;

  char* wbase = (char*)lds + w * 16640;
  char* Bhi = wbase;                    // 32 rows x 64 f16, XOR-swizzled (4096 B)
  char* Blo = wbase + 4096;             // 4096 B
  float* Dw = (float*)(wbase + 8192);   // [64][33] floats (8448 B)

  f16x8 Ah[4][2], Al[4][2];
  #pragma unroll
  for (int mt = 0; mt < 4; ++mt) {
    #pragma unroll
    for (int ks = 0; ks < 2; ++ks) {
      int r = rowbase + mt * 16 + l15;
      Ah[mt][ks] = *(const f16x8*)(xhb + r * 64 + ks * 32 + lg * 8);
      Al[mt][ks] = *(const f16x8*)(xlb + r * 64 + ks * 32 + lg * 8);
    }
  }

  float bd[10]; int bi[10];
  #pragma unroll
  for (int i = 0; i < 10; ++i) { bd[i] = FLT_MAX; bi[i] = 0; }

  int srow[4], scc[4];
  #pragma unroll
  for (int i = 0; i < 4; ++i) { int c = i * 64 + lane; srow[i] = c >> 3; scc[i] = c & 7; }

  f16x8 sh[4], sl[4];
  {
    int mb0 = w * 32;
    #pragma unroll
    for (int i = 0; i < 4; ++i) {
      sh[i] = *(const f16x8*)(xhb + (mb0 + srow[i]) * 64 + scc[i] * 8);
      sl[i] = *(const f16x8*)(xlb + (mb0 + srow[i]) * 64 + scc[i] * 8);
    }
  }

  float* Drow = Dw + lane * 33;

  #pragma unroll 1
  for (int t = 0; t < 32; ++t) {
    const int mb = (t * 4 + w) * 32;
    const int mb2 = (t < 31) ? ((t + 1) * 4 + w) * 32 : mb;
    float sqv0 = sq[bN + mb + l15];
    float sqv1 = sq[bN + mb + 16 + l15];
    #pragma unroll
    for (int i = 0; i < 4; ++i) {
      int off = srow[i] * 128 + 16 * (scc[i] ^ (srow[i] & 7));
      *(f16x8*)(Bhi + off) = sh[i];
      *(f16x8*)(Blo + off) = sl[i];
    }
    #pragma unroll
    for (int i = 0; i < 4; ++i) {
      sh[i] = *(const f16x8*)(xhb + (mb2 + srow[i]) * 64 + scc[i] * 8);
      sl[i] = *(const f16x8*)(xlb + (mb2 + srow[i]) * 64 + scc[i] * 8);
    }
    f16x8 Bh[2][2], Bl[2][2];
    #pragma unroll
    for (int nt = 0; nt < 2; ++nt) {
      #pragma unroll
      for (int ks = 0; ks < 2; ++ks) {
        int rr2 = nt * 16 + l15;
        int off = rr2 * 128 + 16 * ((ks * 4 + lg) ^ (rr2 & 7));
        Bh[nt][ks] = *(const f16x8*)(Bhi + off);
        Bl[nt][ks] = *(const f16x8*)(Blo + off);
      }
    }
    #pragma unroll
    for (int mt = 0; mt < 4; ++mt) {
      f32x4 a0 = {0.f, 0.f, 0.f, 0.f}, a1 = {0.f, 0.f, 0.f, 0.f};
      #pragma unroll
      for (int ks = 0; ks < 2; ++ks) {
        a0 = __builtin_amdgcn_mfma_f32_16x16x32_f16(Ah[mt][ks], Bh[0][ks], a0, 0, 0, 0);
        a1 = __builtin_amdgcn_mfma_f32_16x16x32_f16(Ah[mt][ks], Bh[1][ks], a1, 0, 0, 0);
        a0 = __builtin_amdgcn_mfma_f32_16x16x32_f16(Ah[mt][ks], Bl[0][ks], a0, 0, 0, 0);
        a1 = __builtin_amdgcn_mfma_f32_16x16x32_f16(Ah[mt][ks], Bl[1][ks], a1, 0, 0, 0);
        a0 = __builtin_amdgcn_mfma_f32_16x16x32_f16(Al[mt][ks], Bh[0][ks], a0, 0, 0, 0);
        a1 = __builtin_amdgcn_mfma_f32_16x16x32_f16(Al[mt][ks], Bh[1][ks], a1, 0, 0, 0);
      }
      int rw = mt * 16 + lg * 4;
      #pragma unroll
      for (int r2 = 0; r2 < 4; ++r2) {
        Dw[(rw + r2) * 33 + l15]      = fmaf(-2.f, a0[r2], sqv0);
        Dw[(rw + r2) * 33 + 16 + l15] = fmaf(-2.f, a1[r2], sqv1);
      }
    }
    #pragma unroll 4
    for (int mm = 0; mm < 32; ++mm) {
      float dv = Drow[mm];
      if (dv < bd[9]) {
        float cd = dv; int ci = bN + mb + mm;   // GLOBAL row index
        #pragma unroll
        for (int j = 0; j < 10; ++j) {
          bool swp = cd < bd[j];
          float tf = bd[j]; int ti = bi[j];
          bd[j] = swp ? cd : tf; bi[j] = swp ? ci : ti;
          cd = swp ? tf : cd;    ci = swp ? ti : ci;
        }
      }
    }
  }

  __syncthreads();
  float* md = lds;                   // [4][64][10] dists
  int*   mi = (int*)(lds + 2560);    // [4][64][10] indices
  #pragma unroll
  for (int i = 0; i < 10; ++i) {
    md[(w * 64 + lane) * 10 + i] = bd[i];
    mi[(w * 64 + lane) * 10 + i] = bi[i];
  }
  __syncthreads();
  if (tid < 64) {
    float fd[10]; int fi[10];
    #pragma unroll
    for (int i = 0; i < 10; ++i) { fd[i] = FLT_MAX; fi[i] = 0; }
    for (int w2 = 0; w2 < 4; ++w2) {
      for (int kk = 0; kk < 10; ++kk) {
        float dd2 = md[(w2 * 64 + tid) * 10 + kk];
        int   ii2 = mi[(w2 * 64 + tid) * 10 + kk];
        if (dd2 < fd[9]) {
          float cd = dd2; int ci = ii2;
          #pragma unroll
          for (int j = 0; j < 10; ++j) {
            bool swp = cd < fd[j];
            float tf = fd[j]; int ti = fi[j];
            fd[j] = swp ? cd : tf; fi[j] = swp ? ci : ti;
            cd = swp ? tf : cd;    ci = swp ? ti : ci;
          }
        }
      }
    }
    #pragma unroll
    for (int kk = 0; kk < 10; ++kk)
      knn[(bN + rowbase + tid) * KNBR + kk] = fi[kk];
  }
}

// ---------------- K5: U/V precompute (layer-1 folded per point) ----------------
__global__ void k_uv(const float* __restrict__ xn, const float* __restrict__ W1,
                     const float* __restrict__ b1, float* __restrict__ u,
                     float* __restrict__ v) {
  __shared__ float xs[64 * 64];   // 16 KB
  const int tid = threadIdx.x;
  const int o = tid & 127;
  const bool isU = tid < 128;
  const int rowbase = blockIdx.x * 64;

  float wreg[64];
  #pragma unroll
  for (int d = 0; d < 64; ++d) {
    float bw = W1[(64 + d) * 128 + o];
    wreg[d] = isU ? (W1[d * 128 + o] + bw) : bw;
  }
  const float bb = isU ? b1[o] : 0.f;
  float* __restrict__ dst = isU ? u : v;

  {
    const float4* s4 = (const float4*)(xn + rowbase * 64);
    float4* d4 = (float4*)xs;
    #pragma unroll
    for (int i = 0; i < 4; ++i) d4[tid + 256 * i] = s4[tid + 256 * i];
  }
  __syncthreads();

  for (int r = 0; r < 64; ++r) {
    const float4* xr = (const float4*)(xs + r * 64);
    float a0 = bb, a1 = 0.f, a2 = 0.f, a3 = 0.f;
    #pragma unroll
    for (int q = 0; q < 16; ++q) {
      float4 xv = xr[q];
      a0 = fmaf(xv.x, wreg[4 * q + 0], a0);
      a1 = fmaf(xv.y, wreg[4 * q + 1], a1);
      a2 = fmaf(xv.z, wreg[4 * q + 2], a2);
      a3 = fmaf(xv.w, wreg[4 * q + 3], a3);
    }
    dst[(rowbase + r) * 128 + o] = (a0 + a1) + (a2 + a3);
  }
}

// ---------------- K6: edge MLP via MFMA, barrier-free per-wave ----------------
// Wave owns groups of 8 points: 80 edge rows = 5 exact 16-row M-tiles.
// h1 = relu(U[n]-V[m]) built in f32, cvt f16 into A-frag layout (row=l15,
// k=ks*32+lg*8+j). Layer2: W2 B-frags in VGPRs (col=l15=out). h2 transposed
// through per-wave LDS (wave-internal ordering, no barrier). Layer3: W3^T
// frags from shared LDS. Max over K via LDS atomicMax (floats >=0).
__global__ __launch_bounds__(256, 2) void k_edge(const float* __restrict__ uu,
                                                 const float* __restrict__ vv,
                                                 const int* __restrict__ knn,
                                                 const float* __restrict__ W2,
                                                 const float* __restrict__ b2,
                                                 const float* __restrict__ W3,
                                                 const float* __restrict__ b3,
                                                 float* __restrict__ vert) {
  __shared__ __align__(16) _Float16 W3Ts[64 * 72];        // W3T[out][k2], 9216 B
  __shared__ __align__(16) _Float16 h2buf[4][16 * 88];    // per-wave, 2816 B each
  __shared__ int vmaxs[4][512];                           // per-wave [8 pts][64]
  const int tid = threadIdx.x;
  const int w = tid >> 6, lane = tid & 63;
  const int l15 = lane & 15, lg = lane >> 4;

  // W3T init (block-coop, one-time)
  for (int i = tid; i < 64 * 64; i += 256) {
    int o3 = i >> 6, k2 = i & 63;
    W3Ts[o3 * 72 + k2] = (_Float16)W3[k2 * 64 + o3];
  }
  // W2 B-fragments in registers: frag[ks][nt][j] = W2[(ks*32+lg*8+j)*64 + nt*16+l15]
  f16x8 w2f[4][4];
  #pragma unroll
  for (int ks = 0; ks < 4; ++ks) {
    #pragma unroll
    for (int nt = 0; nt < 4; ++nt) {
      f16x8 t;
      #pragma unroll
      for (int j = 0; j < 8; ++j)
        t[j] = (_Float16)W2[(ks * 32 + lg * 8 + j) * 64 + nt * 16 + l15];
      w2f[ks][nt] = t;
    }
  }
  float bias2[4], bias3[4];
  #pragma unroll
  for (int nt = 0; nt < 4; ++nt) { bias2[nt] = b2[nt * 16 + l15]; bias3[nt] = b3[nt * 16 + l15]; }

  _Float16* h2w = h2buf[w];
  int* vmaxw = vmaxs[w];
  #pragma unroll
  for (int q = 0; q < 8; ++q) vmaxw[lane * 8 + q] = 0;
  __syncthreads();   // only barrier: W3Ts ready

  const int wgid = blockIdx.x * 4 + w;   // 1024 waves, 4096 groups
  for (int j = 0; j < 4; ++j) {
    const int g = wgid * 4 + j;
    const int n0 = g * 8;
    const int ebase = n0 * KNBR;
    #pragma unroll 1
    for (int mt = 0; mt < 5; ++mt) {
      const int e = mt * 16 + l15;
      const int m = knn[ebase + e];
      const int n = n0 + e / 10;
      const float* Up = uu + (size_t)n * 128 + lg * 8;
      const float* Vp = vv + (size_t)m * 128 + lg * 8;
      f16x8 A[4];
      #pragma unroll
      for (int ks = 0; ks < 4; ++ks) {
        float4 ua = *(const float4*)(Up + ks * 32);
        float4 ub = *(const float4*)(Up + ks * 32 + 4);
        float4 va = *(const float4*)(Vp + ks * 32);
        float4 vb = *(const float4*)(Vp + ks * 32 + 4);
        f16x8 t;
        t[0] = (_Float16)fmaxf(ua.x - va.x, 0.f);
        t[1] = (_Float16)fmaxf(ua.y - va.y, 0.f);
        t[2] = (_Float16)fmaxf(ua.z - va.z, 0.f);
        t[3] = (_Float16)fmaxf(ua.w - va.w, 0.f);
        t[4] = (_Float16)fmaxf(ub.x - vb.x, 0.f);
        t[5] = (_Float16)fmaxf(ub.y - vb.y, 0.f);
        t[6] = (_Float16)fmaxf(ub.z - vb.z, 0.f);
        t[7] = (_Float16)fmaxf(ub.w - vb.w, 0.f);
        A[ks] = t;
      }
      f32x4 acc[4];
      #pragma unroll
      for (int nt = 0; nt < 4; ++nt) { float bbv = bias2[nt]; acc[nt] = (f32x4){bbv, bbv, bbv, bbv}; }
      #pragma unroll
      for (int ks = 0; ks < 4; ++ks) {
        #pragma unroll
        for (int nt = 0; nt < 4; ++nt)
          acc[nt] = __builtin_amdgcn_mfma_f32_16x16x32_f16(A[ks], w2f[ks][nt], acc[nt], 0, 0, 0);
      }
      // h2 -> per-wave LDS (row=edge-in-tile, col=out2), relu + f16
      #pragma unroll
      for (int nt = 0; nt < 4; ++nt) {
        #pragma unroll
        for (int r = 0; r < 4; ++r)
          h2w[(lg * 4 + r) * 88 + nt * 16 + l15] = (_Float16)fmaxf(acc[nt][r], 0.f);
      }
      // read back in A-frag layout (wave-internal, in-order DS pipe)
      f16x8 A3[2];
      #pragma unroll
      for (int ks2 = 0; ks2 < 2; ++ks2)
        A3[ks2] = *(const f16x8*)(h2w + l15 * 88 + ks2 * 32 + lg * 8);
      f32x4 c3[4];
      #pragma unroll
      for (int nt = 0; nt < 4; ++nt) { float bbv = bias3[nt]; c3[nt] = (f32x4){bbv, bbv, bbv, bbv}; }
      #pragma unroll
      for (int ks2 = 0; ks2 < 2; ++ks2) {
        #pragma unroll
        for (int nt = 0; nt < 4; ++nt) {
          f16x8 bf = *(const f16x8*)(W3Ts + (nt * 16 + l15) * 72 + ks2 * 32 + lg * 8);
          c3[nt] = __builtin_amdgcn_mfma_f32_16x16x32_f16(A3[ks2], bf, c3[nt], 0, 0, 0);
        }
      }
      // relu + max over K via per-wave LDS atomicMax (values >= 0)
      #pragma unroll
      for (int nt = 0; nt < 4; ++nt) {
        #pragma unroll
        for (int r = 0; r < 4; ++r) {
          float val = fmaxf(c3[nt][r], 0.f);
          int e2 = mt * 16 + lg * 4 + r;
          int p = e2 / 10;
          atomicMax(&vmaxw[p * 64 + nt * 16 + l15], __float_as_int(val));
        }
      }
    }
    // write vert + reset (wave-internal ordering: ds ops in program order)
    {
      int p2 = lane >> 3, c0 = (lane & 7) * 8;
      const int* vp = &vmaxw[p2 * 64 + c0];
      float4 r0, r1;
      r0.x = __int_as_float(vp[0]); r0.y = __int_as_float(vp[1]);
      r0.z = __int_as_float(vp[2]); r0.w = __int_as_float(vp[3]);
      r1.x = __int_as_float(vp[4]); r1.y = __int_as_float(vp[5]);
      r1.z = __int_as_float(vp[6]); r1.w = __int_as_float(vp[7]);
      *(float4*)(vert + (size_t)(n0 + p2) * 64 + c0) = r0;
      *(float4*)(vert + (size_t)(n0 + p2) * 64 + c0 + 4) = r1;
      #pragma unroll
      for (int q = 0; q < 8; ++q) vmaxw[lane * 8 + q] = 0;
    }
  }
}

// ---------------- K7: global max over N per batch ----------------
__global__ void k_gmax(const float* __restrict__ vert, float* __restrict__ g) {
  __shared__ float red[4][64];
  int b = blockIdx.x >> 4, chunk = blockIdx.x & 15;
  int sub = threadIdx.x >> 6, o = threadIdx.x & 63;
  float vm = 0.f;
  for (int j = 0; j < 64; ++j) {
    int r = chunk * 256 + j * 4 + sub;
    vm = fmaxf(vm, vert[(b * NN + r) * 64 + o]);
  }
  red[sub][o] = vm;
  __syncthreads();
  if (sub == 0) {
    float mm = fmaxf(fmaxf(red[0][o], red[1][o]), fmaxf(red[2][o], red[3][o]));
    atomicMax((int*)&g[b * 64 + o], __float_as_int(mm));  // vert >= 0
  }
}

// ---------------- K7b: gb[b] = g[b] @ Wg_bottom + bg ----------------
__global__ void k_gb(const float* __restrict__ g, const float* __restrict__ Wg,
                     const float* __restrict__ bg, float* __restrict__ gb) {
  int t = threadIdx.x;        // 512
  int b = t >> 6, o = t & 63;
  float acc = bg[o];
  #pragma unroll
  for (int i = 0; i < 64; ++i)
    acc = fmaf(g[b * 64 + i], Wg[(64 + i) * 64 + o], acc);
  gb[b * 64 + o] = acc;
}

// ---------------- K8: out = relu(vert @ Wg_top + gb[b]) ----------------
__global__ void k_final(const float* __restrict__ vert, const float* __restrict__ Wg,
                        const float* __restrict__ gb, float* __restrict__ out) {
  __shared__ float Wgs[64 * 64];
  int tid = threadIdx.x, w = tid >> 6, lane = tid & 63;
  for (int i = tid; i < 4096; i += 256) Wgs[i] = Wg[i];
  __syncthreads();
  int gw = blockIdx.x * 4 + w;
  for (int j = 0; j < 4; ++j) {
    int n = gw + 8192 * j;
    int b = n >> 12;
    float vrow = vert[n * 64 + lane];
    float ac0 = gb[b * 64 + lane], ac1 = 0.f, ac2 = 0.f, ac3 = 0.f;
    #pragma unroll
    for (int i = 0; i < 64; i += 4) {
      ac0 = fmaf(__shfl(vrow, i),     Wgs[i * 64 + lane],       ac0);
      ac1 = fmaf(__shfl(vrow, i + 1), Wgs[(i + 1) * 64 + lane], ac1);
      ac2 = fmaf(__shfl(vrow, i + 2), Wgs[(i + 2) * 64 + lane], ac2);
      ac3 = fmaf(__shfl(vrow, i + 3), Wgs[(i + 3) * 64 + lane], ac3);
    }
    out[n * 64 + lane] = fmaxf((ac0 + ac1) + (ac2 + ac3), 0.f);
  }
}

extern "C" void kernel_launch(void* const* d_in, const int* in_sizes, int n_in,
                              void* d_out, int out_size, void* d_ws, size_t ws_size,
                              hipStream_t stream) {
  const float* x     = (const float*)d_in[0];
  const float* gamma = (const float*)d_in[1];
  const float* beta  = (const float*)d_in[2];
  const float* W1    = (const float*)d_in[3];
  const float* b1    = (const float*)d_in[4];
  const float* W2    = (const float*)d_in[5];
  const float* b2    = (const float*)d_in[6];
  const float* W3    = (const float*)d_in[7];
  const float* b3    = (const float*)d_in[8];
  const float* Wg    = (const float*)d_in[9];
  const float* bg    = (const float*)d_in[10];
  float* out = (float*)d_out;

  float* ws    = (float*)d_ws;
  float* stats = ws;                    // 128
  float* ss    = ws + 128;              // 128
  float* xn    = ws + 256;              // 2097152
  float* sq    = xn + 2097152;          // 32768
  int*   knn   = (int*)(sq + 32768);    // 327680 ints
  float* u     = (float*)(knn + 327680);// 4194304
  float* v     = u + 4194304;           // 4194304
  float* vert  = v + 4194304;           // 2097152
  float* g     = vert + 2097152;        // 512
  float* gb    = g + 512;               // 512
  _Float16* xh = (_Float16*)(gb + 512);             // 2097152 halfs (1 M floats)
  _Float16* xl = (_Float16*)(gb + 512 + 1048576);   // 2097152 halfs

  hipMemsetAsync(stats, 0, 128 * sizeof(float), stream);
  hipMemsetAsync(g, 0, 512 * sizeof(float), stream);

  k_bn_stats<<<256, 256, 0, stream>>>(x, stats);
  k_bn_finalize<<<1, 64, 0, stream>>>(stats, gamma, beta, ss);
  k_normalize<<<8192, 256, 0, stream>>>(x, ss, xn, sq, xh, xl);
  k_knn<<<512, 256, 0, stream>>>(xh, xl, sq, knn);
  k_uv<<<512, 256, 0, stream>>>(xn, W1, b1, u, v);
  k_edge<<<256, 256, 0, stream>>>(u, v, knn, W2, b2, W3, b3, vert);
  k_gmax<<<128, 256, 0, stream>>>(vert, g);
  k_gb<<<1, 512, 0, stream>>>(g, Wg, bg, gb);
  k_final<<<2048, 256, 0, stream>>>(vert, Wg, gb, out);
}

// Round 7
// 469.344 us; speedup vs baseline: 4.0006x; 1.0118x over previous
//
#include <hip/hip_runtime.h>
#include <hip/hip_fp16.h>
#include <float.h>

#define BB 8
#define NN 4096
#define DD 64
#define KNBR 10
#define ROWS (BB*NN)   // 32768

typedef _Float16 f16x8 __attribute__((ext_vector_type(8)));
typedef float f32x4 __attribute__((ext_vector_type(4)));

// ---------------- K1: BN stats (sum, sumsq per feature) ----------------
__global__ void k_bn_stats(const float* __restrict__ x, float* __restrict__ stats) {
  __shared__ float ls[2][4][64];
  int d = threadIdx.x & 63;
  int g = threadIdx.x >> 6;
  float s = 0.f, s2 = 0.f;
  for (int r = blockIdx.x * 4 + g; r < ROWS; r += gridDim.x * 4) {
    float val = x[r * 64 + d];
    s += val;
    s2 = fmaf(val, val, s2);
  }
  ls[0][g][d] = s;
  ls[1][g][d] = s2;
  __syncthreads();
  if (g == 0) {
    atomicAdd(&stats[d],      ls[0][0][d] + ls[0][1][d] + ls[0][2][d] + ls[0][3][d]);
    atomicAdd(&stats[64 + d], ls[1][0][d] + ls[1][1][d] + ls[1][2][d] + ls[1][3][d]);
  }
}

// ---------------- K2: finalize scale/shift ----------------
__global__ void k_bn_finalize(const float* __restrict__ stats,
                              const float* __restrict__ gamma,
                              const float* __restrict__ beta,
                              float* __restrict__ ss) {
  int d = threadIdx.x;  // 64 threads
  const float inv = 1.f / 32768.f;
  float mu  = stats[d] * inv;
  float var = stats[64 + d] * inv - mu * mu;
  float sc  = gamma[d] / sqrtf(var + 1e-5f);
  ss[d]      = sc;
  ss[64 + d] = beta[d] - mu * sc;
}

// ---------------- K3: normalize + row sumsq + f16 hi/lo planes ----------------
__global__ void k_normalize(const float* __restrict__ x, const float* __restrict__ ss,
                            float* __restrict__ xn, float* __restrict__ sq,
                            _Float16* __restrict__ xh, _Float16* __restrict__ xl) {
  int row = blockIdx.x * 4 + (threadIdx.x >> 6);
  int d = threadIdx.x & 63;
  int idx = row * 64 + d;
  float val = fmaf(x[idx], ss[d], ss[64 + d]);
  xn[idx] = val;
  _Float16 h = (_Float16)val;
  _Float16 l = (_Float16)(val - (float)h);
  xh[idx] = h;
  xl[idx] = l;
  float p = val * val;
  #pragma unroll
  for (int off = 32; off > 0; off >>= 1) p += __shfl_xor(p, off);
  if (d == 0) sq[row] = p;
}

// ---------------- K4: KNN, exact two-pass ----------------
// Pass A: MFMA dist tiles; per-row top-10 VALUES only (med3 clamp chain).
// Merge: exact per-row 10th-smallest threshold (values-only).
// Pass B: recompute identical MFMA tiles (bit-identical dists); each lane
// tests its own 16 accumulator outputs vs per-row thr; matches append to
// knn via LDS atomic slot counters (order-free; downstream is max-over-K).
__global__ __launch_bounds__(256, 2) void k_knn(const _Float16* __restrict__ xh,
                                                const _Float16* __restrict__ xl,
                                                const float* __restrict__ sq,
                                                int* __restrict__ knn) {
  __shared__ __align__(16) float lds[16640];   // 66560 B = 4 waves x 16640 B
  __shared__ float thrs[64];
  __shared__ int cnts[64];
  const int tid = threadIdx.x;
  const int w = tid >> 6, lane = tid & 63;
  const int l15 = lane & 15, lg = lane >> 4;
  const int b = blockIdx.x >> 6;
  const int rowbase = (blockIdx.x & 63) << 6;
  const int bN = b * NN;
  const _Float16* __restrict__ xhb = xh + (size_t)bN * 64;
  const _Float16* __restrict__ xlb = xl + (size_t)bN * 64;

  char* wbase = (char*)lds + w * 16640;
  char* Bhi = wbase;                    // 32 rows x 64 f16, XOR-swizzled (4096 B)
  char* Blo = wbase + 4096;             // 4096 B
  float* Dw = (float*)(wbase + 8192);   // [64][33] floats (8448 B)

  // A fragments for the block's 64 rows (persistent in VGPRs)
  f16x8 Ah[4][2], Al[4][2];
  #pragma unroll
  for (int mt = 0; mt < 4; ++mt) {
    #pragma unroll
    for (int ks = 0; ks < 2; ++ks) {
      int r = rowbase + mt * 16 + l15;
      Ah[mt][ks] = *(const f16x8*)(xhb + r * 64 + ks * 32 + lg * 8);
      Al[mt][ks] = *(const f16x8*)(xlb + r * 64 + ks * 32 + lg * 8);
    }
  }

  float bd[10];
  #pragma unroll
  for (int i = 0; i < 10; ++i) bd[i] = FLT_MAX;

  int srow[4], scc[4];
  #pragma unroll
  for (int i = 0; i < 4; ++i) { int c = i * 64 + lane; srow[i] = c >> 3; scc[i] = c & 7; }

  f16x8 sh[4], sl[4];
  {
    int mb0 = w * 32;
    #pragma unroll
    for (int i = 0; i < 4; ++i) {
      sh[i] = *(const f16x8*)(xhb + (mb0 + srow[i]) * 64 + scc[i] * 8);
      sl[i] = *(const f16x8*)(xlb + (mb0 + srow[i]) * 64 + scc[i] * 8);
    }
  }

  float* Drow = Dw + lane * 33;

  // ---------------- PASS A: values-only top-10 ----------------
  #pragma unroll 1
  for (int t = 0; t < 32; ++t) {
    const int mb = (t * 4 + w) * 32;
    const int mb2 = (t < 31) ? ((t + 1) * 4 + w) * 32 : mb;
    float sqv0 = sq[bN + mb + l15];
    float sqv1 = sq[bN + mb + 16 + l15];
    #pragma unroll
    for (int i = 0; i < 4; ++i) {
      int off = srow[i] * 128 + 16 * (scc[i] ^ (srow[i] & 7));
      *(f16x8*)(Bhi + off) = sh[i];
      *(f16x8*)(Blo + off) = sl[i];
    }
    #pragma unroll
    for (int i = 0; i < 4; ++i) {
      sh[i] = *(const f16x8*)(xhb + (mb2 + srow[i]) * 64 + scc[i] * 8);
      sl[i] = *(const f16x8*)(xlb + (mb2 + srow[i]) * 64 + scc[i] * 8);
    }
    f16x8 Bh[2][2], Bl[2][2];
    #pragma unroll
    for (int nt = 0; nt < 2; ++nt) {
      #pragma unroll
      for (int ks = 0; ks < 2; ++ks) {
        int rr2 = nt * 16 + l15;
        int off = rr2 * 128 + 16 * ((ks * 4 + lg) ^ (rr2 & 7));
        Bh[nt][ks] = *(const f16x8*)(Bhi + off);
        Bl[nt][ks] = *(const f16x8*)(Blo + off);
      }
    }
    #pragma unroll
    for (int mt = 0; mt < 4; ++mt) {
      f32x4 a0 = {0.f, 0.f, 0.f, 0.f}, a1 = {0.f, 0.f, 0.f, 0.f};
      #pragma unroll
      for (int ks = 0; ks < 2; ++ks) {
        a0 = __builtin_amdgcn_mfma_f32_16x16x32_f16(Ah[mt][ks], Bh[0][ks], a0, 0, 0, 0);
        a1 = __builtin_amdgcn_mfma_f32_16x16x32_f16(Ah[mt][ks], Bh[1][ks], a1, 0, 0, 0);
        a0 = __builtin_amdgcn_mfma_f32_16x16x32_f16(Ah[mt][ks], Bl[0][ks], a0, 0, 0, 0);
        a1 = __builtin_amdgcn_mfma_f32_16x16x32_f16(Ah[mt][ks], Bl[1][ks], a1, 0, 0, 0);
        a0 = __builtin_amdgcn_mfma_f32_16x16x32_f16(Al[mt][ks], Bh[0][ks], a0, 0, 0, 0);
        a1 = __builtin_amdgcn_mfma_f32_16x16x32_f16(Al[mt][ks], Bh[1][ks], a1, 0, 0, 0);
      }
      int rw = mt * 16 + lg * 4;
      #pragma unroll
      for (int r2 = 0; r2 < 4; ++r2) {
        Dw[(rw + r2) * 33 + l15]      = fmaf(-2.f, a0[r2], sqv0);
        Dw[(rw + r2) * 33 + 16 + l15] = fmaf(-2.f, a1[r2], sqv1);
      }
    }
    // values-only insert: min + med3 clamp chain
    #pragma unroll 4
    for (int mm = 0; mm < 32; ++mm) {
      float cd = Drow[mm];
      if (cd < bd[9]) {
        float prev = bd[0];
        bd[0] = fminf(cd, bd[0]);
        #pragma unroll
        for (int j = 1; j < 10; ++j) {
          float cur = bd[j];
          bd[j] = fminf(cur, fmaxf(prev, cd));
          prev = cur;
        }
      }
    }
  }

  // ---------------- merge -> per-row exact 10th-smallest threshold ----------------
  __syncthreads();
  float* md = lds;                   // [4][64][10] dists
  #pragma unroll
  for (int i = 0; i < 10; ++i) md[(w * 64 + lane) * 10 + i] = bd[i];
  if (tid < 64) cnts[tid] = 0;
  __syncthreads();
  if (tid < 64) {
    float fd[10];
    #pragma unroll
    for (int i = 0; i < 10; ++i) fd[i] = FLT_MAX;
    for (int w2 = 0; w2 < 4; ++w2) {
      #pragma unroll
      for (int kk = 0; kk < 10; ++kk) {
        float cd = md[(w2 * 64 + tid) * 10 + kk];
        if (cd < fd[9]) {
          float prev = fd[0];
          fd[0] = fminf(cd, fd[0]);
          #pragma unroll
          for (int j = 1; j < 10; ++j) {
            float cur = fd[j];
            fd[j] = fminf(cur, fmaxf(prev, cd));
            prev = cur;
          }
        }
      }
    }
    thrs[tid] = fd[9];
  }
  __syncthreads();

  // preload per-row thresholds for this lane's 16 output rows
  float thv[4][4];
  #pragma unroll
  for (int mt = 0; mt < 4; ++mt)
    #pragma unroll
    for (int r2 = 0; r2 < 4; ++r2)
      thv[mt][r2] = thrs[mt * 16 + lg * 4 + r2];

  int* knnrow = knn + (size_t)(bN + rowbase) * KNBR;

  // ---------------- PASS B: recompute + threshold-append ----------------
  {
    int mb0 = w * 32;
    #pragma unroll
    for (int i = 0; i < 4; ++i) {
      sh[i] = *(const f16x8*)(xhb + (mb0 + srow[i]) * 64 + scc[i] * 8);
      sl[i] = *(const f16x8*)(xlb + (mb0 + srow[i]) * 64 + scc[i] * 8);
    }
  }
  #pragma unroll 1
  for (int t = 0; t < 32; ++t) {
    const int mb = (t * 4 + w) * 32;
    const int mb2 = (t < 31) ? ((t + 1) * 4 + w) * 32 : mb;
    float sqv0 = sq[bN + mb + l15];
    float sqv1 = sq[bN + mb + 16 + l15];
    #pragma unroll
    for (int i = 0; i < 4; ++i) {
      int off = srow[i] * 128 + 16 * (scc[i] ^ (srow[i] & 7));
      *(f16x8*)(Bhi + off) = sh[i];
      *(f16x8*)(Blo + off) = sl[i];
    }
    #pragma unroll
    for (int i = 0; i < 4; ++i) {
      sh[i] = *(const f16x8*)(xhb + (mb2 + srow[i]) * 64 + scc[i] * 8);
      sl[i] = *(const f16x8*)(xlb + (mb2 + srow[i]) * 64 + scc[i] * 8);
    }
    f16x8 Bh[2][2], Bl[2][2];
    #pragma unroll
    for (int nt = 0; nt < 2; ++nt) {
      #pragma unroll
      for (int ks = 0; ks < 2; ++ks) {
        int rr2 = nt * 16 + l15;
        int off = rr2 * 128 + 16 * ((ks * 4 + lg) ^ (rr2 & 7));
        Bh[nt][ks] = *(const f16x8*)(Bhi + off);
        Bl[nt][ks] = *(const f16x8*)(Blo + off);
      }
    }
    #pragma unroll
    for (int mt = 0; mt < 4; ++mt) {
      f32x4 a0 = {0.f, 0.f, 0.f, 0.f}, a1 = {0.f, 0.f, 0.f, 0.f};
      #pragma unroll
      for (int ks = 0; ks < 2; ++ks) {
        a0 = __builtin_amdgcn_mfma_f32_16x16x32_f16(Ah[mt][ks], Bh[0][ks], a0, 0, 0, 0);
        a1 = __builtin_amdgcn_mfma_f32_16x16x32_f16(Ah[mt][ks], Bh[1][ks], a1, 0, 0, 0);
        a0 = __builtin_amdgcn_mfma_f32_16x16x32_f16(Ah[mt][ks], Bl[0][ks], a0, 0, 0, 0);
        a1 = __builtin_amdgcn_mfma_f32_16x16x32_f16(Ah[mt][ks], Bl[1][ks], a1, 0, 0, 0);
        a0 = __builtin_amdgcn_mfma_f32_16x16x32_f16(Al[mt][ks], Bh[0][ks], a0, 0, 0, 0);
        a1 = __builtin_amdgcn_mfma_f32_16x16x32_f16(Al[mt][ks], Bh[1][ks], a1, 0, 0, 0);
      }
      // lane tests its own outputs: row = mt*16+lg*4+r2, m = mb + l15 (+16)
      #pragma unroll
      for (int r2 = 0; r2 < 4; ++r2) {
        float d0 = fmaf(-2.f, a0[r2], sqv0);
        float d1 = fmaf(-2.f, a1[r2], sqv1);
        int row = mt * 16 + lg * 4 + r2;
        if (d0 <= thv[mt][r2]) {
          int slot = atomicAdd(&cnts[row], 1);
          if (slot < KNBR) knnrow[row * KNBR + slot] = bN + mb + l15;
        }
        if (d1 <= thv[mt][r2]) {
          int slot = atomicAdd(&cnts[row], 1);
          if (slot < KNBR) knnrow[row * KNBR + slot] = bN + mb + 16 + l15;
        }
      }
    }
  }
}

// ---------------- K5: U/V precompute (layer-1 folded per point) ----------------
__global__ void k_uv(const float* __restrict__ xn, const float* __restrict__ W1,
                     const float* __restrict__ b1, float* __restrict__ u,
                     float* __restrict__ v) {
  __shared__ float xs[64 * 64];   // 16 KB
  const int tid = threadIdx.x;
  const int o = tid & 127;
  const bool isU = tid < 128;
  const int rowbase = blockIdx.x * 64;

  float wreg[64];
  #pragma unroll
  for (int d = 0; d < 64; ++d) {
    float bw = W1[(64 + d) * 128 + o];
    wreg[d] = isU ? (W1[d * 128 + o] + bw) : bw;
  }
  const float bb = isU ? b1[o] : 0.f;
  float* __restrict__ dst = isU ? u : v;

  {
    const float4* s4 = (const float4*)(xn + rowbase * 64);
    float4* d4 = (float4*)xs;
    #pragma unroll
    for (int i = 0; i < 4; ++i) d4[tid + 256 * i] = s4[tid + 256 * i];
  }
  __syncthreads();

  for (int r = 0; r < 64; ++r) {
    const float4* xr = (const float4*)(xs + r * 64);
    float a0 = bb, a1 = 0.f, a2 = 0.f, a3 = 0.f;
    #pragma unroll
    for (int q = 0; q < 16; ++q) {
      float4 xv = xr[q];
      a0 = fmaf(xv.x, wreg[4 * q + 0], a0);
      a1 = fmaf(xv.y, wreg[4 * q + 1], a1);
      a2 = fmaf(xv.z, wreg[4 * q + 2], a2);
      a3 = fmaf(xv.w, wreg[4 * q + 3], a3);
    }
    dst[(rowbase + r) * 128 + o] = (a0 + a1) + (a2 + a3);
  }
}

// ---------------- K6: edge MLP via MFMA, barrier-free per-wave ----------------
__global__ __launch_bounds__(256, 2) void k_edge(const float* __restrict__ uu,
                                                 const float* __restrict__ vv,
                                                 const int* __restrict__ knn,
                                                 const float* __restrict__ W2,
                                                 const float* __restrict__ b2,
                                                 const float* __restrict__ W3,
                                                 const float* __restrict__ b3,
                                                 float* __restrict__ vert) {
  __shared__ __align__(16) _Float16 W3Ts[64 * 72];        // W3T[out][k2], 9216 B
  __shared__ __align__(16) _Float16 h2buf[4][16 * 88];    // per-wave, 2816 B each
  __shared__ int vmaxs[4][512];                           // per-wave [8 pts][64]
  const int tid = threadIdx.x;
  const int w = tid >> 6, lane = tid & 63;
  const int l15 = lane & 15, lg = lane >> 4;

  for (int i = tid; i < 64 * 64; i += 256) {
    int o3 = i >> 6, k2 = i & 63;
    W3Ts[o3 * 72 + k2] = (_Float16)W3[k2 * 64 + o3];
  }
  f16x8 w2f[4][4];
  #pragma unroll
  for (int ks = 0; ks < 4; ++ks) {
    #pragma unroll
    for (int nt = 0; nt < 4; ++nt) {
      f16x8 t;
      #pragma unroll
      for (int j = 0; j < 8; ++j)
        t[j] = (_Float16)W2[(ks * 32 + lg * 8 + j) * 64 + nt * 16 + l15];
      w2f[ks][nt] = t;
    }
  }
  float bias2[4], bias3[4];
  #pragma unroll
  for (int nt = 0; nt < 4; ++nt) { bias2[nt] = b2[nt * 16 + l15]; bias3[nt] = b3[nt * 16 + l15]; }

  _Float16* h2w = h2buf[w];
  int* vmaxw = vmaxs[w];
  #pragma unroll
  for (int q = 0; q < 8; ++q) vmaxw[lane * 8 + q] = 0;
  __syncthreads();   // only barrier: W3Ts ready

  const int wgid = blockIdx.x * 4 + w;   // 1024 waves, 4096 groups
  for (int j = 0; j < 4; ++j) {
    const int g = wgid * 4 + j;
    const int n0 = g * 8;
    const int ebase = n0 * KNBR;
    #pragma unroll 1
    for (int mt = 0; mt < 5; ++mt) {
      const int e = mt * 16 + l15;
      const int m = knn[ebase + e];
      const int n = n0 + e / 10;
      const float* Up = uu + (size_t)n * 128 + lg * 8;
      const float* Vp = vv + (size_t)m * 128 + lg * 8;
      f16x8 A[4];
      #pragma unroll
      for (int ks = 0; ks < 4; ++ks) {
        float4 ua = *(const float4*)(Up + ks * 32);
        float4 ub = *(const float4*)(Up + ks * 32 + 4);
        float4 va = *(const float4*)(Vp + ks * 32);
        float4 vb = *(const float4*)(Vp + ks * 32 + 4);
        f16x8 t;
        t[0] = (_Float16)fmaxf(ua.x - va.x, 0.f);
        t[1] = (_Float16)fmaxf(ua.y - va.y, 0.f);
        t[2] = (_Float16)fmaxf(ua.z - va.z, 0.f);
        t[3] = (_Float16)fmaxf(ua.w - va.w, 0.f);
        t[4] = (_Float16)fmaxf(ub.x - vb.x, 0.f);
        t[5] = (_Float16)fmaxf(ub.y - vb.y, 0.f);
        t[6] = (_Float16)fmaxf(ub.z - vb.z, 0.f);
        t[7] = (_Float16)fmaxf(ub.w - vb.w, 0.f);
        A[ks] = t;
      }
      f32x4 acc[4];
      #pragma unroll
      for (int nt = 0; nt < 4; ++nt) { float bbv = bias2[nt]; acc[nt] = (f32x4){bbv, bbv, bbv, bbv}; }
      #pragma unroll
      for (int ks = 0; ks < 4; ++ks) {
        #pragma unroll
        for (int nt = 0; nt < 4; ++nt)
          acc[nt] = __builtin_amdgcn_mfma_f32_16x16x32_f16(A[ks], w2f[ks][nt], acc[nt], 0, 0, 0);
      }
      #pragma unroll
      for (int nt = 0; nt < 4; ++nt) {
        #pragma unroll
        for (int r = 0; r < 4; ++r)
          h2w[(lg * 4 + r) * 88 + nt * 16 + l15] = (_Float16)fmaxf(acc[nt][r], 0.f);
      }
      f16x8 A3[2];
      #pragma unroll
      for (int ks2 = 0; ks2 < 2; ++ks2)
        A3[ks2] = *(const f16x8*)(h2w + l15 * 88 + ks2 * 32 + lg * 8);
      f32x4 c3[4];
      #pragma unroll
      for (int nt = 0; nt < 4; ++nt) { float bbv = bias3[nt]; c3[nt] = (f32x4){bbv, bbv, bbv, bbv}; }
      #pragma unroll
      for (int ks2 = 0; ks2 < 2; ++ks2) {
        #pragma unroll
        for (int nt = 0; nt < 4; ++nt) {
          f16x8 bf = *(const f16x8*)(W3Ts + (nt * 16 + l15) * 72 + ks2 * 32 + lg * 8);
          c3[nt] = __builtin_amdgcn_mfma_f32_16x16x32_f16(A3[ks2], bf, c3[nt], 0, 0, 0);
        }
      }
      #pragma unroll
      for (int nt = 0; nt < 4; ++nt) {
        #pragma unroll
        for (int r = 0; r < 4; ++r) {
          float val = fmaxf(c3[nt][r], 0.f);
          int e2 = mt * 16 + lg * 4 + r;
          int p = e2 / 10;
          atomicMax(&vmaxw[p * 64 + nt * 16 + l15], __float_as_int(val));
        }
      }
    }
    {
      int p2 = lane >> 3, c0 = (lane & 7) * 8;
      const int* vp = &vmaxw[p2 * 64 + c0];
      float4 r0, r1;
      r0.x = __int_as_float(vp[0]); r0.y = __int_as_float(vp[1]);
      r0.z = __int_as_float(vp[2]); r0.w = __int_as_float(vp[3]);
      r1.x = __int_as_float(vp[4]); r1.y = __int_as_float(vp[5]);
      r1.z = __int_as_float(vp[6]); r1.w = __int_as_float(vp[7]);
      *(float4*)(vert + (size_t)(n0 + p2) * 64 + c0) = r0;
      *(float4*)(vert + (size_t)(n0 + p2) * 64 + c0 + 4) = r1;
      #pragma unroll
      for (int q = 0; q < 8; ++q) vmaxw[lane * 8 + q] = 0;
    }
  }
}

// ---------------- K7: global max over N per batch ----------------
__global__ void k_gmax(const float* __restrict__ vert, float* __restrict__ g) {
  __shared__ float red[4][64];
  int b = blockIdx.x >> 4, chunk = blockIdx.x & 15;
  int sub = threadIdx.x >> 6, o = threadIdx.x & 63;
  float vm = 0.f;
  for (int j = 0; j < 64; ++j) {
    int r = chunk * 256 + j * 4 + sub;
    vm = fmaxf(vm, vert[(b * NN + r) * 64 + o]);
  }
  red[sub][o] = vm;
  __syncthreads();
  if (sub == 0) {
    float mm = fmaxf(fmaxf(red[0][o], red[1][o]), fmaxf(red[2][o], red[3][o]));
    atomicMax((int*)&g[b * 64 + o], __float_as_int(mm));  // vert >= 0
  }
}

// ---------------- K7b: gb[b] = g[b] @ Wg_bottom + bg ----------------
__global__ void k_gb(const float* __restrict__ g, const float* __restrict__ Wg,
                     const float* __restrict__ bg, float* __restrict__ gb) {
  int t = threadIdx.x;        // 512
  int b = t >> 6, o = t & 63;
  float acc = bg[o];
  #pragma unroll
  for (int i = 0; i < 64; ++i)
    acc = fmaf(g[b * 64 + i], Wg[(64 + i) * 64 + o], acc);
  gb[b * 64 + o] = acc;
}

// ---------------- K8: out = relu(vert @ Wg_top + gb[b]) ----------------
__global__ void k_final(const float* __restrict__ vert, const float* __restrict__ Wg,
                        const float* __restrict__ gb, float* __restrict__ out) {
  __shared__ float Wgs[64 * 64];
  int tid = threadIdx.x, w = tid >> 6, lane = tid & 63;
  for (int i = tid; i < 4096; i += 256) Wgs[i] = Wg[i];
  __syncthreads();
  int gw = blockIdx.x * 4 + w;
  for (int j = 0; j < 4; ++j) {
    int n = gw + 8192 * j;
    int b = n >> 12;
    float vrow = vert[n * 64 + lane];
    float ac0 = gb[b * 64 + lane], ac1 = 0.f, ac2 = 0.f, ac3 = 0.f;
    #pragma unroll
    for (int i = 0; i < 64; i += 4) {
      ac0 = fmaf(__shfl(vrow, i),     Wgs[i * 64 + lane],       ac0);
      ac1 = fmaf(__shfl(vrow, i + 1), Wgs[(i + 1) * 64 + lane], ac1);
      ac2 = fmaf(__shfl(vrow, i + 2), Wgs[(i + 2) * 64 + lane], ac2);
      ac3 = fmaf(__shfl(vrow, i + 3), Wgs[(i + 3) * 64 + lane], ac3);
    }
    out[n * 64 + lane] = fmaxf((ac0 + ac1) + (ac2 + ac3), 0.f);
  }
}

extern "C" void kernel_launch(void* const* d_in, const int* in_sizes, int n_in,
                              void* d_out, int out_size, void* d_ws, size_t ws_size,
                              hipStream_t stream) {
  const float* x     = (const float*)d_in[0];
  const float* gamma = (const float*)d_in[1];
  const float* beta  = (const float*)d_in[2];
  const float* W1    = (const float*)d_in[3];
  const float* b1    = (const float*)d_in[4];
  const float* W2    = (const float*)d_in[5];
  const float* b2    = (const float*)d_in[6];
  const float* W3    = (const float*)d_in[7];
  const float* b3    = (const float*)d_in[8];
  const float* Wg    = (const float*)d_in[9];
  const float* bg    = (const float*)d_in[10];
  float* out = (float*)d_out;

  float* ws    = (float*)d_ws;
  float* stats = ws;                    // 128
  float* ss    = ws + 128;              // 128
  float* xn    = ws + 256;              // 2097152
  float* sq    = xn + 2097152;          // 32768
  int*   knn   = (int*)(sq + 32768);    // 327680 ints
  float* u     = (float*)(knn + 327680);// 4194304
  float* v     = u + 4194304;           // 4194304
  float* vert  = v + 4194304;           // 2097152
  float* g     = vert + 2097152;        // 512
  float* gb    = g + 512;               // 512
  _Float16* xh = (_Float16*)(gb + 512);             // 2097152 halfs (1 M floats)
  _Float16* xl = (_Float16*)(gb + 512 + 1048576);   // 2097152 halfs

  hipMemsetAsync(stats, 0, 128 * sizeof(float), stream);
  hipMemsetAsync(g, 0, 512 * sizeof(float), stream);

  k_bn_stats<<<256, 256, 0, stream>>>(x, stats);
  k_bn_finalize<<<1, 64, 0, stream>>>(stats, gamma, beta, ss);
  k_normalize<<<8192, 256, 0, stream>>>(x, ss, xn, sq, xh, xl);
  k_knn<<<512, 256, 0, stream>>>(xh, xl, sq, knn);
  k_uv<<<512, 256, 0, stream>>>(xn, W1, b1, u, v);
  k_edge<<<256, 256, 0, stream>>>(u, v, knn, W2, b2, W3, b3, vert);
  k_gmax<<<128, 256, 0, stream>>>(vert, g);
  k_gb<<<1, 512, 0, stream>>>(g, Wg, bg, gb);
  k_final<<<2048, 256, 0, stream>>>(vert, Wg, gb, out);
}